// Round 15
// baseline (123.116 us; speedup 1.0000x reference)
//
#include <hip/hip_runtime.h>
#include <hip/hip_bf16.h>
#include <math.h>

typedef __bf16 bf16;
typedef __bf16 bf16x8 __attribute__((ext_vector_type(8)));
typedef __bf16 bf16x4 __attribute__((ext_vector_type(4)));
typedef float f32x4 __attribute__((ext_vector_type(4)));
typedef float f32x16 __attribute__((ext_vector_type(16)));

#define DEV __device__ __forceinline__
#define AS1(p) ((const __attribute__((address_space(1))) void*)(p))
#define AS3(p) ((__attribute__((address_space(3))) void*)(p))

// ---------------- problem sizes ----------------
#define Bsz 2
#define Lseq 2048
#define Dm 1024
#define Hh 16
#define HD 64
#define BL (Bsz * Lseq)   // 4096 rows
#define TN (3 * Dm)       // 3072

#define LOG2E 1.44269504088896f

// ---------------- workspace layout (bytes) ----------------
#define OFF_XATT  ((size_t)0)                            // xbf bf16 8.39MB; att aliases after gemm1
#define OFF_WQKVT (OFF_XATT  + (size_t)BL * Dm * 2)      // 6.29MB
#define OFF_WOUTT (OFF_WQKVT + (size_t)TN * Dm * 2)      // 2.10MB
#define OFF_TAB   (OFF_WOUTT + (size_t)Dm * Dm * 2)      // 0.52MB
#define OFF_Q     (OFF_TAB   + (size_t)Lseq * 32 * 8)    // 8.39MB q bf16 [32][2048][64]
#define OFF_K     (OFF_Q     + (size_t)BL * Dm * 2)      // 8.39MB
#define OFF_VT    (OFF_K     + (size_t)BL * Dm * 2)      // 8.39MB vT bf16 [32][64][2048]
// end = 42.5 MB

DEV float exp2_fast(float x) {   // 2^x, single v_exp_f32
    float r;
    asm("v_exp_f32 %0, %1" : "=v"(r) : "v"(x));
    return r;
}
// v_permlane32_swap_b32 a,b: a = {a.lo, b.lo}, b = {a.hi, b.hi}.
// ONLY safe when a and b hold DISTINCT live values (R9 post-mortem).
// R11: no hand-written pk/max3 trees (operand-marshal movs regressed).
// R14: fixed-shift (max-free) softmax FAILED validation (absmax 0.23) --
// keep the running-max online softmax; mechanism unresolved, do not retry
// without on-device probing.
DEV void plswap(unsigned& a, unsigned& b) {
    asm("v_permlane32_swap_b32 %0, %1" : "+v"(a), "+v"(b));
}

// ---------------- fused prep: convert + 2 transposes + sincos table --------
// R11 win (-8.8us): one kernel, 4 block-ranges, stages run concurrently.
#define NB_CONV 2048              // (BL*Dm/8)/256
#define NB_TQ   3072              // (TN/32)*(Dm/32)
#define NB_TO   1024              // (Dm/32)*(Dm/32)
#define NB_SC   256               // Lseq*32/256
__global__ __launch_bounds__(256) void k_prep(const float* __restrict__ x,
                                              const float* __restrict__ Wqkv,
                                              const float* __restrict__ Wout,
                                              bf16* __restrict__ xbf,
                                              bf16* __restrict__ wqkvT,
                                              bf16* __restrict__ woutT,
                                              float2* __restrict__ tab) {
    const int bb = blockIdx.x;
    const int tid = threadIdx.x;
    if (bb < NB_CONV) {
        int i = bb * 256 + tid;
        const float4* in4 = (const float4*)x;
        float4 a = in4[i * 2], b = in4[i * 2 + 1];
        bf16x8 o;
        o[0] = (bf16)a.x; o[1] = (bf16)a.y; o[2] = (bf16)a.z; o[3] = (bf16)a.w;
        o[4] = (bf16)b.x; o[5] = (bf16)b.y; o[6] = (bf16)b.z; o[7] = (bf16)b.w;
        ((bf16x8*)xbf)[i] = o;
    } else if (bb < NB_CONV + NB_TQ + NB_TO) {
        const bool isQ = bb < NB_CONV + NB_TQ;
        const int lb = isQ ? bb - NB_CONV : bb - (NB_CONV + NB_TQ);
        const int nx = isQ ? (TN / 32) : (Dm / 32);
        const int C = isQ ? TN : Dm;           // R = Dm for both
        const float* in = isQ ? Wqkv : Wout;
        bf16* out = isQ ? wqkvT : woutT;
        __shared__ float t[32][33];
        const int bx = (lb % nx) * 32, by = (lb / nx) * 32;
        const int tx = tid & 31, ty = tid >> 5;
#pragma unroll
        for (int i = 0; i < 32; i += 8)
            t[ty + i][tx] = in[(size_t)(by + ty + i) * C + bx + tx];
        __syncthreads();
#pragma unroll
        for (int i = 0; i < 32; i += 8)
            out[(size_t)(bx + ty + i) * Dm + by + tx] = (bf16)t[tx][ty + i];
    } else {
        int idx = (bb - (NB_CONV + NB_TQ + NB_TO)) * 256 + tid;
        int pos = idx >> 5, tt = idx & 31;
        float theta = powf(10000.0f, -(float)tt * (1.0f / 32.0f));
        float f = (float)pos * theta;
        tab[idx] = make_float2(sinf(f), cosf(f));
    }
}

DEV f32x4 mfma16(bf16x8 a, bf16x8 b, f32x4 c) {
    return __builtin_amdgcn_mfma_f32_16x16x32_bf16(a, b, c, 0, 0, 0);
}

// ------------- 256x256 QKV GEMM, 8 waves, dbuf 128KB dynamic LDS (R13 win) -
__global__ __launch_bounds__(512, 2) void k_gemm_qkv256(
        const bf16* __restrict__ A, const bf16* __restrict__ BT,
        const float* __restrict__ bias,
        bf16* __restrict__ qo, bf16* __restrict__ ko, bf16* __restrict__ vt,
        const float2* __restrict__ tab) {
    extern __shared__ char dynlds[];   // 131072 B: buf[2] x (A 32KB | B 32KB)
    const int tid = threadIdx.x;
    const int wid = tid >> 6, lane = tid & 63;
    const int lg = lane >> 4, lr = lane & 15;
    const int wr = wid >> 2, wc = wid & 3;     // wave = (wr 0..1) x (wc 0..3)
    const int id = blockIdx.x;
    const int id2 = (id & 7) * 24 + (id >> 3);
    const int n0 = (id2 % 12) * 256;
    const int m0 = (id2 / 12) * 256;
    const char* Ab = (const char*)A;
    const char* Bb = (const char*)BT;
    const size_t Kb = (size_t)Dm * 2;

    f32x4 acc[8][4] = {};

    const int rowL = lane >> 3;
    const int j16 = ((lane & 7) ^ rowL) * 16;  // pre-swizzled source chunk

    auto STAGE = [&](char* buf, int kt) {
        char* Al = buf;
        char* Bl = buf + 32768;
#pragma unroll
        for (int c = 0; c < 4; ++c) {
            const int g = wid * 4 + c;         // 8-row group 0..31
            const int row = g * 8 + rowL;
            __builtin_amdgcn_global_load_lds(
                AS1(Ab + (size_t)(m0 + row) * Kb + kt * 128 + j16),
                AS3(Al + g * 1024), 16, 0, 0);
            __builtin_amdgcn_global_load_lds(
                AS1(Bb + (size_t)(n0 + row) * Kb + kt * 128 + j16),
                AS3(Bl + g * 1024), 16, 0, 0);
        }
    };
    auto COMPUTE = [&](const char* buf) {
        const char* Al = buf + wr * 16384;
        const char* Bl = buf + 32768 + wc * 8192;
        __builtin_amdgcn_s_setprio(1);
#pragma unroll
        for (int kf = 0; kf < 2; ++kf) {
            bf16x8 af[8], bfr[4];
#pragma unroll
            for (int i = 0; i < 8; ++i) {
                const int ra = i * 16 + lr;
                af[i] = *(const bf16x8*)(Al + ra * 128 + ((kf * 64 + lg * 16) ^ ((ra & 7) << 4)));
            }
#pragma unroll
            for (int j = 0; j < 4; ++j) {
                const int rb = j * 16 + lr;
                bfr[j] = *(const bf16x8*)(Bl + rb * 128 + ((kf * 64 + lg * 16) ^ ((rb & 7) << 4)));
            }
#pragma unroll
            for (int i = 0; i < 8; ++i)
#pragma unroll
                for (int j = 0; j < 4; ++j)
                    acc[i][j] = mfma16(af[i], bfr[j], acc[i][j]);
        }
        __builtin_amdgcn_s_setprio(0);
    };

    STAGE(dynlds, 0);
    __syncthreads();
#pragma unroll 1
    for (int t = 0; t < 16; ++t) {
        char* cur = dynlds + (size_t)(t & 1) * 65536;
        if (t < 15) STAGE(dynlds + (size_t)((t & 1) ^ 1) * 65536, t + 1);
        COMPUTE(cur);
        __syncthreads();
    }

    // ---- fused epilogue: RoPE q (scaled 1/8*log2e), RoPE k, transposed vT --
    const int ph = n0 >> 10;                   // 0=q 1=k 2=v (block-uniform)
    const int c0 = n0 + wc * 64;
    const int h = (c0 & 1023) >> 6;
    const int lrow0 = m0 + wr * 128;
    const int b = lrow0 >> 11;
    const int bh = b * 16 + h;
    const int lbase = lrow0 & 2047;
    float bv[4];
#pragma unroll
    for (int j = 0; j < 4; ++j) bv[j] = bias[c0 + j * 16 + lr];
    float* Lw = (float*)(dynlds + wid * 4096);   // per-wave 16x64 fp32 slab

#pragma unroll   // FULL unroll: compile-time acc indices (rule #20)
    for (int i = 0; i < 8; ++i) {
#pragma unroll
        for (int j = 0; j < 4; ++j)
#pragma unroll
            for (int r = 0; r < 4; ++r)
                Lw[(lg * 4 + r) * 64 + j * 16 + lr] = acc[i][j][r] + bv[j];
        __syncthreads();
        if (ph < 2) {
            const float scale = (ph == 0) ? 0.125f * LOG2E : 1.0f;
            bf16* dst = (ph == 0 ? qo : ko) + (size_t)bh * Lseq * 64;
#pragma unroll
            for (int j = 0; j < 4; ++j)
#pragma unroll
                for (int r = 0; r < 4; ++r) {
                    int rl = lg * 4 + r;
                    int d = j * 16 + lr;
                    int l = lbase + i * 16 + rl;
                    float v = Lw[rl * 64 + d];
                    int dp = (d < 32) ? (2 * d + 1) : (2 * d - 64);
                    float p = Lw[rl * 64 + dp];
                    float2 f = tab[l * 32 + (d & 31)];
                    float val = ((d < 32) ? (v - p) * f.x : (v + p) * f.y) * scale;
                    dst[(size_t)l * 64 + d] = (bf16)val;
                }
        } else {
            int d = lane;
            int lb = lbase + i * 16;
            bf16x8 o1, o2;
#pragma unroll
            for (int rw = 0; rw < 8; ++rw) {
                o1[rw] = (bf16)Lw[rw * 64 + d];
                o2[rw] = (bf16)Lw[(rw + 8) * 64 + d];
            }
            bf16* dst = vt + ((size_t)bh * 64 + d) * Lseq + lb;
            *(bf16x8*)dst = o1;
            *(bf16x8*)(dst + 8) = o2;
        }
        __syncthreads();
    }
}

// ---------------- bf16 GEMM, 128x128 tile, BK=64 (output projection) -------
__global__ __launch_bounds__(256) void k_gemm_out(const bf16* __restrict__ A,
                                                  const bf16* __restrict__ BT,
                                                  const float* __restrict__ bias,
                                                  float* __restrict__ C) {
    __shared__ uint4 smem4[2048];   // 32KB: A tile 16KB + B tile 16KB
    char* Al = (char*)smem4;
    char* Bl = (char*)smem4 + 16384;
    const int tid = threadIdx.x;
    const int w = tid >> 6, lane = tid & 63, lg = lane >> 4, lr = lane & 15;
    const int id = blockIdx.x;
    const int id2 = (id & 7) * 32 + (id >> 3);    // 256 blocks, 32/XCD
    const int n0 = (id2 & 7) * 128;               // Dm/128 = 8
    const int m0 = (id2 >> 3) * 128;
    const int wm = (w >> 1) * 64, wn = (w & 1) * 64;
    const char* Ab = (const char*)A;
    const char* Bb = (const char*)BT;
    const size_t Kb = (size_t)Dm * 2;

    f32x4 acc[4][4] = {};

    const int rowL = lane >> 3;
    const int j16 = ((lane & 7) ^ rowL) * 16;

    for (int kt = 0; kt < Dm; kt += 64) {
#pragma unroll
        for (int c = 0; c < 4; ++c) {
            const int R0 = (w * 4 + c) * 8;
            const int row = R0 + rowL;
            __builtin_amdgcn_global_load_lds(AS1(Ab + (size_t)(m0 + row) * Kb + kt * 2 + j16),
                                             AS3(Al + R0 * 128), 16, 0, 0);
            __builtin_amdgcn_global_load_lds(AS1(Bb + (size_t)(n0 + row) * Kb + kt * 2 + j16),
                                             AS3(Bl + R0 * 128), 16, 0, 0);
        }
        __syncthreads();
#pragma unroll
        for (int kf = 0; kf < 2; ++kf) {
            bf16x8 af[4], bfr[4];
#pragma unroll
            for (int i = 0; i < 4; ++i) {
                int ra = wm + i * 16 + lr;
                af[i] = *(const bf16x8*)(Al + ra * 128 + ((kf * 64 + lg * 16) ^ ((ra & 7) << 4)));
                int rb = wn + i * 16 + lr;
                bfr[i] = *(const bf16x8*)(Bl + rb * 128 + ((kf * 64 + lg * 16) ^ ((rb & 7) << 4)));
            }
#pragma unroll
            for (int i = 0; i < 4; ++i)
#pragma unroll
                for (int j = 0; j < 4; ++j)
                    acc[i][j] = mfma16(af[i], bfr[j], acc[i][j]);
        }
        __syncthreads();
    }

#pragma unroll
    for (int i = 0; i < 4; ++i) {
        int row = m0 + wm + i * 16 + lg * 4;
#pragma unroll
        for (int j = 0; j < 4; ++j) {
            int col = n0 + wn + j * 16 + lr;
            float bv = bias[col];
#pragma unroll
            for (int r = 0; r < 4; ++r)
                C[(size_t)(row + r) * Dm + col] = acc[i][j][r] + bv;
        }
    }
}

// ---------------- stage 3: flash attention (swapped-operand, 32x32x16) ------
// R15 = R13/R10 attn body verbatim (57.7us known-good): running-max online
// softmax (defer-max THR=8), serial reductions, permlane P-exchange,
// double-buffered K/V via global_load_lds, in-block KV-split + LSE combine.
DEV f32x16 mfma32(bf16x8 a, bf16x8 b, f32x16 c) {
    return __builtin_amdgcn_mfma_f32_32x32x16_bf16(a, b, c, 0, 0, 0);
}
DEV unsigned packbf(float lo, float hi) {
    unsigned short a = __builtin_bit_cast(unsigned short, (bf16)lo);
    unsigned short b = __builtin_bit_cast(unsigned short, (bf16)hi);
    return (unsigned)a | ((unsigned)b << 16);
}

DEV void stage_k(const char* kb, char* dst, int j0, int qw, int lane) {
#pragma unroll
    for (int c = 0; c < 2; ++c) {
        const int j = qw * 2 + c;              // chunk 0..7 (wave-uniform)
        const int rsw = lane ^ j;              // pre-swizzled source row
        __builtin_amdgcn_global_load_lds(AS1(kb + (size_t)(j0 + rsw) * 128 + j * 16),
                                         AS3(dst + j * 1024), 16, 0, 0);
    }
}
DEV void stage_v(const char* vb, char* dst, int j0, int qw, int lane) {
#pragma unroll
    for (int c = 0; c < 2; ++c) {
        const int j = qw * 2 + c;
        const int rsw = lane ^ j;
        __builtin_amdgcn_global_load_lds(AS1(vb + (size_t)rsw * 4096 + (size_t)j0 * 2 + j * 16),
                                         AS3(dst + j * 1024), 16, 0, 0);
    }
}

__global__ __launch_bounds__(512, 4) void k_attn(const bf16* __restrict__ Q,
                                                 const bf16* __restrict__ Kt,
                                                 const bf16* __restrict__ Vt,
                                                 bf16* __restrict__ Op) {
    __shared__ uint4 smem4[4096];   // 64KB: 2 halves x (2 bufs x [K 8K | V 8K])
    char* base = (char*)smem4;
    const int tid = threadIdx.x;
    const int w = tid >> 6, lane = tid & 63;
    const int qw = w & 3, s = w >> 2;
    const int hi = lane >> 5, l31 = lane & 31;
    const int bid = blockIdx.x;
    const int bh = bid >> 4, qt = bid & 15;
    const int q0 = qt * 128 + qw * 32;
    const char* qb = (const char*)(Q + (size_t)bh * Lseq * 64);
    const char* kb = (const char*)(Kt + (size_t)bh * Lseq * 64);
    const char* vb = (const char*)(Vt + (size_t)bh * 64 * Lseq);
    char* setb = base + s * 32768;             // this half's pipeline
    const int jbase = s * 16;                  // this half's first tile index

    // Q frags (B-operand): elem i = Q[q0+l31][kst*16 + hi*8 + i]
    bf16x8 qf[4];
#pragma unroll
    for (int kst = 0; kst < 4; ++kst)
        qf[kst] = *(const bf16x8*)(qb + (size_t)(q0 + l31) * 128 + kst * 32 + hi * 16);

    f32x16 o0 = {}, o1 = {};
    float m = -1e30f, lsum = 0.f;

    // prologue: stage tile 0 of this half into buf 0
    stage_k(kb, setb, jbase * 64, qw, lane);
    stage_v(vb, setb + 8192, jbase * 64, qw, lane);
    __syncthreads();

    for (int t = 0; t < 16; ++t) {
        const int cur = t & 1;
        const char* Kl = setb + cur * 16384;
        const char* Vl = Kl + 8192;
        char* Kn = setb + (cur ^ 1) * 16384;
        char* Vn = Kn + 8192;

        // async-stage next tile (drains at this iteration's end barrier)
        if (t < 15) {
            stage_k(kb, Kn, (jbase + t + 1) * 64, qw, lane);
            stage_v(vb, Vn, (jbase + t + 1) * 64, qw, lane);
        }

        // S^T = K * Q^T : s0 = j rows 0..31, s1 = 32..63 (col q = l31)
        f32x16 s0 = {}, s1 = {};
        __builtin_amdgcn_s_setprio(1);
#pragma unroll
        for (int kst = 0; kst < 4; ++kst) {
            const int jK = kst * 2 + hi;
            const int x = l31 ^ jK;            // jK<8: flips low 3 bits only
            bf16x8 ka = *(const bf16x8*)(Kl + jK * 1024 + x * 16);
            bf16x8 kc = *(const bf16x8*)(Kl + jK * 1024 + (32 + x) * 16);
            s0 = mfma32(ka, qf[kst], s0);
            s1 = mfma32(kc, qf[kst], s1);
        }
        __builtin_amdgcn_s_setprio(0);

        // lane-local online softmax (exp2 domain) for row q = l31
        float pm = fmaxf(s0[0], s0[1]);
#pragma unroll
        for (int r = 2; r < 16; ++r) pm = fmaxf(pm, s0[r]);
#pragma unroll
        for (int r = 0; r < 16; ++r) pm = fmaxf(pm, s1[r]);
        pm = fmaxf(pm, __shfl_xor(pm, 32));
        if (!__all(pm <= m + 8.0f)) {          // defer-max (T13), log2 units
            float mn = fmaxf(m, pm);
            float sc = exp2_fast(m - mn);
#pragma unroll
            for (int r = 0; r < 16; ++r) { o0[r] *= sc; o1[r] *= sc; }
            lsum *= sc; m = mn;
        }
        float rs = 0.f;
#pragma unroll
        for (int r = 0; r < 16; ++r) { s0[r] = exp2_fast(s0[r] - m); rs += s0[r]; }
#pragma unroll
        for (int r = 0; r < 16; ++r) { s1[r] = exp2_fast(s1[r] - m); rs += s1[r]; }
        rs += __shfl_xor(rs, 32);
        lsum += rs;

        // pack P to bf16 pairs; cross-half exchange = 8 in-place permlane
        // swaps on DISTINCT-valued register pairs (safe; see plswap note)
        unsigned u[16];
#pragma unroll
        for (int t2 = 0; t2 < 8; ++t2) {
            u[t2]     = packbf(s0[2 * t2], s0[2 * t2 + 1]);
            u[8 + t2] = packbf(s1[2 * t2], s1[2 * t2 + 1]);
        }
        bf16x8 pf[2][2];
#pragma unroll
        for (int J = 0; J < 2; ++J)
#pragma unroll
            for (int st = 0; st < 2; ++st) {
                const int t0 = J * 8 + st * 4;
                plswap(u[t0 + 0], u[t0 + 2]);
                plswap(u[t0 + 1], u[t0 + 3]);
                union { unsigned wd[4]; bf16x8 v; } f;
                f.wd[0] = u[t0 + 0];
                f.wd[1] = u[t0 + 1];
                f.wd[2] = u[t0 + 2];
                f.wd[3] = u[t0 + 3];
                pf[J][st] = f.v;
            }

        // O^T += V^T * P^T : o0 = d rows 0..31, o1 = 32..63 (col q = l31)
        __builtin_amdgcn_s_setprio(1);
#pragma unroll
        for (int J = 0; J < 2; ++J)
#pragma unroll
            for (int st = 0; st < 2; ++st) {
                const int jV = J * 4 + st * 2 + hi;
                const int x = l31 ^ jV;
                bf16x8 v0 = *(const bf16x8*)(Vl + jV * 1024 + x * 16);
                bf16x8 v1 = *(const bf16x8*)(Vl + jV * 1024 + (32 + x) * 16);
                o0 = mfma32(v0, pf[J][st], o0);
                o1 = mfma32(v1, pf[J][st], o1);
            }
        __builtin_amdgcn_s_setprio(0);
        __syncthreads();
    }

    // ---- combine the two KV halves (LDS exchange; K/V buffers now dead) ----
    float* ex = (float*)base;                   // per qw-wave region: 2176 floats
    if (s == 1) {
        float* r = ex + qw * 2176;
#pragma unroll
        for (int t = 0; t < 16; ++t) {
            r[t * 64 + lane] = o0[t];
            r[1024 + t * 64 + lane] = o1[t];
        }
        r[2048 + lane] = m;
        r[2112 + lane] = lsum;
    }
    __syncthreads();
    if (s == 0) {
        float* r = ex + qw * 2176;
        const float mb = r[2048 + lane], lb = r[2112 + lane];
        const float M = fmaxf(m, mb);
        const float wa = exp2_fast(m - M), wb = exp2_fast(mb - M);
        const float inv = 1.0f / (wa * lsum + wb * lb);
        const float fa = wa * inv, fb = wb * inv;
        const int b = bh >> 4, h = bh & 15;
        bf16* dst = Op + (size_t)(b * Lseq + q0 + l31) * Dm + h * 64;
        // epilogue layout: lane owns col q = l31; rows d = (r&3)+8*(r>>2)+4*hi
#pragma unroll
        for (int t = 0; t < 4; ++t) {
            bf16x4 p0, p1;
#pragma unroll
            for (int i = 0; i < 4; ++i) {
                p0[i] = (bf16)(o0[4 * t + i] * fa + r[(4 * t + i) * 64 + lane] * fb);
                p1[i] = (bf16)(o1[4 * t + i] * fa + r[1024 + (4 * t + i) * 64 + lane] * fb);
            }
            *(bf16x4*)(dst + 8 * t + 4 * hi) = p0;
            *(bf16x4*)(dst + 32 + 8 * t + 4 * hi) = p1;
        }
    }
}

// ---------------- launch ----------------
extern "C" void kernel_launch(void* const* d_in, const int* in_sizes, int n_in,
                              void* d_out, int out_size, void* d_ws, size_t ws_size,
                              hipStream_t stream) {
    (void)in_sizes; (void)n_in; (void)out_size; (void)ws_size;
    const float* x    = (const float*)d_in[0];
    const float* Wqkv = (const float*)d_in[1];
    const float* bqkv = (const float*)d_in[2];
    const float* Wout = (const float*)d_in[3];
    const float* bout = (const float*)d_in[4];
    float* out = (float*)d_out;
    char* ws = (char*)d_ws;

    bf16* xbf    = (bf16*)(ws + OFF_XATT);
    bf16* att    = (bf16*)(ws + OFF_XATT);   // aliases xbf (dead after gemm_qkv)
    bf16* wqkvT  = (bf16*)(ws + OFF_WQKVT);
    bf16* woutT  = (bf16*)(ws + OFF_WOUTT);
    float2* tab  = (float2*)(ws + OFF_TAB);
    bf16* qb     = (bf16*)(ws + OFF_Q);
    bf16* kb     = (bf16*)(ws + OFF_K);
    bf16* vt     = (bf16*)(ws + OFF_VT);

    (void)hipFuncSetAttribute((const void*)k_gemm_qkv256,
                              hipFuncAttributeMaxDynamicSharedMemorySize, 131072);

    hipLaunchKernelGGL(k_prep, dim3(NB_CONV + NB_TQ + NB_TO + NB_SC), dim3(256), 0, stream,
                       x, Wqkv, Wout, xbf, wqkvT, woutT, tab);
    hipLaunchKernelGGL(k_gemm_qkv256, dim3(192), dim3(512), 131072, stream,
                       xbf, wqkvT, bqkv, qb, kb, vt, tab);
    hipLaunchKernelGGL(k_attn, dim3(32 * 16), dim3(512), 0, stream, qb, kb, vt, att);
    hipLaunchKernelGGL(k_gemm_out, dim3((Dm / 128) * (BL / 128)), dim3(256), 0, stream,
                       att, woutT, bout, out);
}

// Round 16
// 119.894 us; speedup vs baseline: 1.0269x; 1.0269x over previous
//
#include <hip/hip_runtime.h>
#include <hip/hip_bf16.h>
#include <math.h>

typedef __bf16 bf16;
typedef __bf16 bf16x8 __attribute__((ext_vector_type(8)));
typedef __bf16 bf16x4 __attribute__((ext_vector_type(4)));
typedef __bf16 bf16x2 __attribute__((ext_vector_type(2)));
typedef float f32x4 __attribute__((ext_vector_type(4)));
typedef float f32x16 __attribute__((ext_vector_type(16)));

#define DEV __device__ __forceinline__
#define AS1(p) ((const __attribute__((address_space(1))) void*)(p))
#define AS3(p) ((__attribute__((address_space(3))) void*)(p))

// ---------------- problem sizes ----------------
#define Bsz 2
#define Lseq 2048
#define Dm 1024
#define Hh 16
#define HD 64
#define BL (Bsz * Lseq)   // 4096 rows
#define TN (3 * Dm)       // 3072

#define LOG2E 1.44269504088896f

// ---------------- workspace layout (bytes) ----------------
#define OFF_XATT  ((size_t)0)                            // xbf bf16 8.39MB; att aliases after gemm1
#define OFF_WQKVT (OFF_XATT  + (size_t)BL * Dm * 2)      // 6.29MB
#define OFF_WOUTT (OFF_WQKVT + (size_t)TN * Dm * 2)      // 2.10MB
#define OFF_TAB   (OFF_WOUTT + (size_t)Dm * Dm * 2)      // 0.52MB
#define OFF_Q     (OFF_TAB   + (size_t)Lseq * 32 * 8)    // 8.39MB q bf16 [32][2048][64]
#define OFF_K     (OFF_Q     + (size_t)BL * Dm * 2)      // 8.39MB
#define OFF_VT    (OFF_K     + (size_t)BL * Dm * 2)      // 8.39MB vT bf16 [32][64][2048]
// end = 42.5 MB

DEV float exp2_fast(float x) {   // 2^x, single v_exp_f32
    float r;
    asm("v_exp_f32 %0, %1" : "=v"(r) : "v"(x));
    return r;
}
// v_permlane32_swap_b32 a,b: a = {a.lo, b.lo}, b = {a.hi, b.hi}.
// ONLY safe when a and b hold DISTINCT live values (R9 post-mortem).
// R11: no hand-written pk/max3 asm trees (operand-marshal movs regressed).
// R14: fixed-shift (max-free) softmax FAILED validation -- keep running max.
DEV void plswap(unsigned& a, unsigned& b) {
    asm("v_permlane32_swap_b32 %0, %1" : "+v"(a), "+v"(b));
}

// ---------------- fused prep: convert + 2 transposes + sincos table --------
// R11 win (-8.8us): one kernel, 4 block-ranges, stages run concurrently.
#define NB_CONV 2048              // (BL*Dm/8)/256
#define NB_TQ   3072              // (TN/32)*(Dm/32)
#define NB_TO   1024              // (Dm/32)*(Dm/32)
#define NB_SC   256               // Lseq*32/256
__global__ __launch_bounds__(256) void k_prep(const float* __restrict__ x,
                                              const float* __restrict__ Wqkv,
                                              const float* __restrict__ Wout,
                                              bf16* __restrict__ xbf,
                                              bf16* __restrict__ wqkvT,
                                              bf16* __restrict__ woutT,
                                              float2* __restrict__ tab) {
    const int bb = blockIdx.x;
    const int tid = threadIdx.x;
    if (bb < NB_CONV) {
        int i = bb * 256 + tid;
        const float4* in4 = (const float4*)x;
        float4 a = in4[i * 2], b = in4[i * 2 + 1];
        bf16x8 o;
        o[0] = (bf16)a.x; o[1] = (bf16)a.y; o[2] = (bf16)a.z; o[3] = (bf16)a.w;
        o[4] = (bf16)b.x; o[5] = (bf16)b.y; o[6] = (bf16)b.z; o[7] = (bf16)b.w;
        ((bf16x8*)xbf)[i] = o;
    } else if (bb < NB_CONV + NB_TQ + NB_TO) {
        const bool isQ = bb < NB_CONV + NB_TQ;
        const int lb = isQ ? bb - NB_CONV : bb - (NB_CONV + NB_TQ);
        const int nx = isQ ? (TN / 32) : (Dm / 32);
        const int C = isQ ? TN : Dm;           // R = Dm for both
        const float* in = isQ ? Wqkv : Wout;
        bf16* out = isQ ? wqkvT : woutT;
        __shared__ float t[32][33];
        const int bx = (lb % nx) * 32, by = (lb / nx) * 32;
        const int tx = tid & 31, ty = tid >> 5;
#pragma unroll
        for (int i = 0; i < 32; i += 8)
            t[ty + i][tx] = in[(size_t)(by + ty + i) * C + bx + tx];
        __syncthreads();
#pragma unroll
        for (int i = 0; i < 32; i += 8)
            out[(size_t)(bx + ty + i) * Dm + by + tx] = (bf16)t[tx][ty + i];
    } else {
        int idx = (bb - (NB_CONV + NB_TQ + NB_TO)) * 256 + tid;
        int pos = idx >> 5, tt = idx & 31;
        float theta = powf(10000.0f, -(float)tt * (1.0f / 32.0f));
        float f = (float)pos * theta;
        tab[idx] = make_float2(sinf(f), cosf(f));
    }
}

DEV f32x4 mfma16(bf16x8 a, bf16x8 b, f32x4 c) {
    return __builtin_amdgcn_mfma_f32_16x16x32_bf16(a, b, c, 0, 0, 0);
}

// ------------- 256x256 QKV GEMM, 8 waves, dbuf 128KB dynamic LDS (R13 win) -
__global__ __launch_bounds__(512, 2) void k_gemm_qkv256(
        const bf16* __restrict__ A, const bf16* __restrict__ BT,
        const float* __restrict__ bias,
        bf16* __restrict__ qo, bf16* __restrict__ ko, bf16* __restrict__ vt,
        const float2* __restrict__ tab) {
    extern __shared__ char dynlds[];   // 131072 B: buf[2] x (A 32KB | B 32KB)
    const int tid = threadIdx.x;
    const int wid = tid >> 6, lane = tid & 63;
    const int lg = lane >> 4, lr = lane & 15;
    const int wr = wid >> 2, wc = wid & 3;     // wave = (wr 0..1) x (wc 0..3)
    const int id = blockIdx.x;
    const int id2 = (id & 7) * 24 + (id >> 3);
    const int n0 = (id2 % 12) * 256;
    const int m0 = (id2 / 12) * 256;
    const char* Ab = (const char*)A;
    const char* Bb = (const char*)BT;
    const size_t Kb = (size_t)Dm * 2;

    f32x4 acc[8][4] = {};

    const int rowL = lane >> 3;
    const int j16 = ((lane & 7) ^ rowL) * 16;  // pre-swizzled source chunk

    auto STAGE = [&](char* buf, int kt) {
        char* Al = buf;
        char* Bl = buf + 32768;
#pragma unroll
        for (int c = 0; c < 4; ++c) {
            const int g = wid * 4 + c;         // 8-row group 0..31
            const int row = g * 8 + rowL;
            __builtin_amdgcn_global_load_lds(
                AS1(Ab + (size_t)(m0 + row) * Kb + kt * 128 + j16),
                AS3(Al + g * 1024), 16, 0, 0);
            __builtin_amdgcn_global_load_lds(
                AS1(Bb + (size_t)(n0 + row) * Kb + kt * 128 + j16),
                AS3(Bl + g * 1024), 16, 0, 0);
        }
    };
    auto COMPUTE = [&](const char* buf) {
        const char* Al = buf + wr * 16384;
        const char* Bl = buf + 32768 + wc * 8192;
        __builtin_amdgcn_s_setprio(1);
#pragma unroll
        for (int kf = 0; kf < 2; ++kf) {
            bf16x8 af[8], bfr[4];
#pragma unroll
            for (int i = 0; i < 8; ++i) {
                const int ra = i * 16 + lr;
                af[i] = *(const bf16x8*)(Al + ra * 128 + ((kf * 64 + lg * 16) ^ ((ra & 7) << 4)));
            }
#pragma unroll
            for (int j = 0; j < 4; ++j) {
                const int rb = j * 16 + lr;
                bfr[j] = *(const bf16x8*)(Bl + rb * 128 + ((kf * 64 + lg * 16) ^ ((rb & 7) << 4)));
            }
#pragma unroll
            for (int i = 0; i < 8; ++i)
#pragma unroll
                for (int j = 0; j < 4; ++j)
                    acc[i][j] = mfma16(af[i], bfr[j], acc[i][j]);
        }
        __builtin_amdgcn_s_setprio(0);
    };

    STAGE(dynlds, 0);
    __syncthreads();
#pragma unroll 1
    for (int t = 0; t < 16; ++t) {
        char* cur = dynlds + (size_t)(t & 1) * 65536;
        if (t < 15) STAGE(dynlds + (size_t)((t & 1) ^ 1) * 65536, t + 1);
        COMPUTE(cur);
        __syncthreads();
    }

    // ---- fused epilogue: RoPE q (scaled 1/8*log2e), RoPE k, transposed vT --
    const int ph = n0 >> 10;                   // 0=q 1=k 2=v (block-uniform)
    const int c0 = n0 + wc * 64;
    const int h = (c0 & 1023) >> 6;
    const int lrow0 = m0 + wr * 128;
    const int b = lrow0 >> 11;
    const int bh = b * 16 + h;
    const int lbase = lrow0 & 2047;
    float bv[4];
#pragma unroll
    for (int j = 0; j < 4; ++j) bv[j] = bias[c0 + j * 16 + lr];
    float* Lw = (float*)(dynlds + wid * 4096);   // per-wave 16x64 fp32 slab

#pragma unroll   // FULL unroll: compile-time acc indices (rule #20)
    for (int i = 0; i < 8; ++i) {
#pragma unroll
        for (int j = 0; j < 4; ++j)
#pragma unroll
            for (int r = 0; r < 4; ++r)
                Lw[(lg * 4 + r) * 64 + j * 16 + lr] = acc[i][j][r] + bv[j];
        __syncthreads();
        if (ph < 2) {
            const float scale = (ph == 0) ? 0.125f * LOG2E : 1.0f;
            bf16* dst = (ph == 0 ? qo : ko) + (size_t)bh * Lseq * 64;
#pragma unroll
            for (int j = 0; j < 4; ++j)
#pragma unroll
                for (int r = 0; r < 4; ++r) {
                    int rl = lg * 4 + r;
                    int d = j * 16 + lr;
                    int l = lbase + i * 16 + rl;
                    float v = Lw[rl * 64 + d];
                    int dp = (d < 32) ? (2 * d + 1) : (2 * d - 64);
                    float p = Lw[rl * 64 + dp];
                    float2 f = tab[l * 32 + (d & 31)];
                    float val = ((d < 32) ? (v - p) * f.x : (v + p) * f.y) * scale;
                    dst[(size_t)l * 64 + d] = (bf16)val;
                }
        } else {
            int d = lane;
            int lb = lbase + i * 16;
            bf16x8 o1, o2;
#pragma unroll
            for (int rw = 0; rw < 8; ++rw) {
                o1[rw] = (bf16)Lw[rw * 64 + d];
                o2[rw] = (bf16)Lw[(rw + 8) * 64 + d];
            }
            bf16* dst = vt + ((size_t)bh * 64 + d) * Lseq + lb;
            *(bf16x8*)dst = o1;
            *(bf16x8*)(dst + 8) = o2;
        }
        __syncthreads();
    }
}

// ---------------- bf16 GEMM, 128x128 tile, BK=64 (output projection) -------
__global__ __launch_bounds__(256) void k_gemm_out(const bf16* __restrict__ A,
                                                  const bf16* __restrict__ BT,
                                                  const float* __restrict__ bias,
                                                  float* __restrict__ C) {
    __shared__ uint4 smem4[2048];   // 32KB: A tile 16KB + B tile 16KB
    char* Al = (char*)smem4;
    char* Bl = (char*)smem4 + 16384;
    const int tid = threadIdx.x;
    const int w = tid >> 6, lane = tid & 63, lg = lane >> 4, lr = lane & 15;
    const int id = blockIdx.x;
    const int id2 = (id & 7) * 32 + (id >> 3);    // 256 blocks, 32/XCD
    const int n0 = (id2 & 7) * 128;               // Dm/128 = 8
    const int m0 = (id2 >> 3) * 128;
    const int wm = (w >> 1) * 64, wn = (w & 1) * 64;
    const char* Ab = (const char*)A;
    const char* Bb = (const char*)BT;
    const size_t Kb = (size_t)Dm * 2;

    f32x4 acc[4][4] = {};

    const int rowL = lane >> 3;
    const int j16 = ((lane & 7) ^ rowL) * 16;

    for (int kt = 0; kt < Dm; kt += 64) {
#pragma unroll
        for (int c = 0; c < 4; ++c) {
            const int R0 = (w * 4 + c) * 8;
            const int row = R0 + rowL;
            __builtin_amdgcn_global_load_lds(AS1(Ab + (size_t)(m0 + row) * Kb + kt * 2 + j16),
                                             AS3(Al + R0 * 128), 16, 0, 0);
            __builtin_amdgcn_global_load_lds(AS1(Bb + (size_t)(n0 + row) * Kb + kt * 2 + j16),
                                             AS3(Bl + R0 * 128), 16, 0, 0);
        }
        __syncthreads();
#pragma unroll
        for (int kf = 0; kf < 2; ++kf) {
            bf16x8 af[4], bfr[4];
#pragma unroll
            for (int i = 0; i < 4; ++i) {
                int ra = wm + i * 16 + lr;
                af[i] = *(const bf16x8*)(Al + ra * 128 + ((kf * 64 + lg * 16) ^ ((ra & 7) << 4)));
                int rb = wn + i * 16 + lr;
                bfr[i] = *(const bf16x8*)(Bl + rb * 128 + ((kf * 64 + lg * 16) ^ ((rb & 7) << 4)));
            }
#pragma unroll
            for (int i = 0; i < 4; ++i)
#pragma unroll
                for (int j = 0; j < 4; ++j)
                    acc[i][j] = mfma16(af[i], bfr[j], acc[i][j]);
        }
        __syncthreads();
    }

#pragma unroll
    for (int i = 0; i < 4; ++i) {
        int row = m0 + wm + i * 16 + lg * 4;
#pragma unroll
        for (int j = 0; j < 4; ++j) {
            int col = n0 + wn + j * 16 + lr;
            float bv = bias[col];
#pragma unroll
            for (int r = 0; r < 4; ++r)
                C[(size_t)(row + r) * Dm + col] = acc[i][j][r] + bv;
        }
    }
}

// ---------------- stage 3: flash attention (swapped-operand, 32x32x16) ------
// R16 = R15 body with two local, semantics-preserving VALU cuts:
//  (1) packbf via bf16x2 bit_cast (canonical form the compiler fuses to
//      v_cvt_pk_bf16_f32; old shift/or form defeated the fusion ~4 inst->1)
//  (2) max/sum reductions reassociated into 4 independent chains (plain C,
//      depth 31->9; no asm/pk per R11 lesson).
DEV f32x16 mfma32(bf16x8 a, bf16x8 b, f32x16 c) {
    return __builtin_amdgcn_mfma_f32_32x32x16_bf16(a, b, c, 0, 0, 0);
}
DEV unsigned packbf(float lo, float hi) {
    bf16x2 v;
    v[0] = (bf16)lo;
    v[1] = (bf16)hi;
    return __builtin_bit_cast(unsigned, v);   // little-endian: v[0] = low 16b
}

DEV void stage_k(const char* kb, char* dst, int j0, int qw, int lane) {
#pragma unroll
    for (int c = 0; c < 2; ++c) {
        const int j = qw * 2 + c;              // chunk 0..7 (wave-uniform)
        const int rsw = lane ^ j;              // pre-swizzled source row
        __builtin_amdgcn_global_load_lds(AS1(kb + (size_t)(j0 + rsw) * 128 + j * 16),
                                         AS3(dst + j * 1024), 16, 0, 0);
    }
}
DEV void stage_v(const char* vb, char* dst, int j0, int qw, int lane) {
#pragma unroll
    for (int c = 0; c < 2; ++c) {
        const int j = qw * 2 + c;
        const int rsw = lane ^ j;
        __builtin_amdgcn_global_load_lds(AS1(vb + (size_t)rsw * 4096 + (size_t)j0 * 2 + j * 16),
                                         AS3(dst + j * 1024), 16, 0, 0);
    }
}

__global__ __launch_bounds__(512, 4) void k_attn(const bf16* __restrict__ Q,
                                                 const bf16* __restrict__ Kt,
                                                 const bf16* __restrict__ Vt,
                                                 bf16* __restrict__ Op) {
    __shared__ uint4 smem4[4096];   // 64KB: 2 halves x (2 bufs x [K 8K | V 8K])
    char* base = (char*)smem4;
    const int tid = threadIdx.x;
    const int w = tid >> 6, lane = tid & 63;
    const int qw = w & 3, s = w >> 2;
    const int hi = lane >> 5, l31 = lane & 31;
    const int bid = blockIdx.x;
    const int bh = bid >> 4, qt = bid & 15;
    const int q0 = qt * 128 + qw * 32;
    const char* qb = (const char*)(Q + (size_t)bh * Lseq * 64);
    const char* kb = (const char*)(Kt + (size_t)bh * Lseq * 64);
    const char* vb = (const char*)(Vt + (size_t)bh * 64 * Lseq);
    char* setb = base + s * 32768;             // this half's pipeline
    const int jbase = s * 16;                  // this half's first tile index

    // Q frags (B-operand): elem i = Q[q0+l31][kst*16 + hi*8 + i]
    bf16x8 qf[4];
#pragma unroll
    for (int kst = 0; kst < 4; ++kst)
        qf[kst] = *(const bf16x8*)(qb + (size_t)(q0 + l31) * 128 + kst * 32 + hi * 16);

    f32x16 o0 = {}, o1 = {};
    float m = -1e30f, lsum = 0.f;

    // prologue: stage tile 0 of this half into buf 0
    stage_k(kb, setb, jbase * 64, qw, lane);
    stage_v(vb, setb + 8192, jbase * 64, qw, lane);
    __syncthreads();

    for (int t = 0; t < 16; ++t) {
        const int cur = t & 1;
        const char* Kl = setb + cur * 16384;
        const char* Vl = Kl + 8192;
        char* Kn = setb + (cur ^ 1) * 16384;
        char* Vn = Kn + 8192;

        // async-stage next tile (drains at this iteration's end barrier)
        if (t < 15) {
            stage_k(kb, Kn, (jbase + t + 1) * 64, qw, lane);
            stage_v(vb, Vn, (jbase + t + 1) * 64, qw, lane);
        }

        // S^T = K * Q^T : s0 = j rows 0..31, s1 = 32..63 (col q = l31)
        f32x16 s0 = {}, s1 = {};
        __builtin_amdgcn_s_setprio(1);
#pragma unroll
        for (int kst = 0; kst < 4; ++kst) {
            const int jK = kst * 2 + hi;
            const int x = l31 ^ jK;            // jK<8: flips low 3 bits only
            bf16x8 ka = *(const bf16x8*)(Kl + jK * 1024 + x * 16);
            bf16x8 kc = *(const bf16x8*)(Kl + jK * 1024 + (32 + x) * 16);
            s0 = mfma32(ka, qf[kst], s0);
            s1 = mfma32(kc, qf[kst], s1);
        }
        __builtin_amdgcn_s_setprio(0);

        // row-max: 4 independent chains (depth 7) + combine (depth 2)
        float cA = s0[0], cB = s0[8], cC = s1[0], cD = s1[8];
#pragma unroll
        for (int r = 1; r < 8; ++r) {
            cA = fmaxf(cA, s0[r]);
            cB = fmaxf(cB, s0[8 + r]);
            cC = fmaxf(cC, s1[r]);
            cD = fmaxf(cD, s1[8 + r]);
        }
        float pm = fmaxf(fmaxf(cA, cB), fmaxf(cC, cD));
        pm = fmaxf(pm, __shfl_xor(pm, 32));
        if (!__all(pm <= m + 8.0f)) {          // defer-max (T13), log2 units
            float mn = fmaxf(m, pm);
            float sc = exp2_fast(m - mn);
#pragma unroll
            for (int r = 0; r < 16; ++r) { o0[r] *= sc; o1[r] *= sc; }
            lsum *= sc; m = mn;
        }
        // exp + row-sum: 4 independent accumulation chains
        float rA = 0.f, rB = 0.f, rC = 0.f, rD = 0.f;
#pragma unroll
        for (int r = 0; r < 8; ++r) {
            s0[r]     = exp2_fast(s0[r] - m);     rA += s0[r];
            s0[8 + r] = exp2_fast(s0[8 + r] - m); rB += s0[8 + r];
            s1[r]     = exp2_fast(s1[r] - m);     rC += s1[r];
            s1[8 + r] = exp2_fast(s1[8 + r] - m); rD += s1[8 + r];
        }
        float rs = (rA + rB) + (rC + rD);
        rs += __shfl_xor(rs, 32);
        lsum += rs;

        // pack P to bf16 pairs (cvt_pk-fusable form); cross-half exchange =
        // 8 in-place permlane swaps on DISTINCT-valued register pairs
        unsigned u[16];
#pragma unroll
        for (int t2 = 0; t2 < 8; ++t2) {
            u[t2]     = packbf(s0[2 * t2], s0[2 * t2 + 1]);
            u[8 + t2] = packbf(s1[2 * t2], s1[2 * t2 + 1]);
        }
        bf16x8 pf[2][2];
#pragma unroll
        for (int J = 0; J < 2; ++J)
#pragma unroll
            for (int st = 0; st < 2; ++st) {
                const int t0 = J * 8 + st * 4;
                plswap(u[t0 + 0], u[t0 + 2]);
                plswap(u[t0 + 1], u[t0 + 3]);
                union { unsigned wd[4]; bf16x8 v; } f;
                f.wd[0] = u[t0 + 0];
                f.wd[1] = u[t0 + 1];
                f.wd[2] = u[t0 + 2];
                f.wd[3] = u[t0 + 3];
                pf[J][st] = f.v;
            }

        // O^T += V^T * P^T : o0 = d rows 0..31, o1 = 32..63 (col q = l31)
        __builtin_amdgcn_s_setprio(1);
#pragma unroll
        for (int J = 0; J < 2; ++J)
#pragma unroll
            for (int st = 0; st < 2; ++st) {
                const int jV = J * 4 + st * 2 + hi;
                const int x = l31 ^ jV;
                bf16x8 v0 = *(const bf16x8*)(Vl + jV * 1024 + x * 16);
                bf16x8 v1 = *(const bf16x8*)(Vl + jV * 1024 + (32 + x) * 16);
                o0 = mfma32(v0, pf[J][st], o0);
                o1 = mfma32(v1, pf[J][st], o1);
            }
        __builtin_amdgcn_s_setprio(0);
        __syncthreads();
    }

    // ---- combine the two KV halves (LDS exchange; K/V buffers now dead) ----
    float* ex = (float*)base;                   // per qw-wave region: 2176 floats
    if (s == 1) {
        float* r = ex + qw * 2176;
#pragma unroll
        for (int t = 0; t < 16; ++t) {
            r[t * 64 + lane] = o0[t];
            r[1024 + t * 64 + lane] = o1[t];
        }
        r[2048 + lane] = m;
        r[2112 + lane] = lsum;
    }
    __syncthreads();
    if (s == 0) {
        float* r = ex + qw * 2176;
        const float mb = r[2048 + lane], lb = r[2112 + lane];
        const float M = fmaxf(m, mb);
        const float wa = exp2_fast(m - M), wb = exp2_fast(mb - M);
        const float inv = 1.0f / (wa * lsum + wb * lb);
        const float fa = wa * inv, fb = wb * inv;
        const int b = bh >> 4, h = bh & 15;
        bf16* dst = Op + (size_t)(b * Lseq + q0 + l31) * Dm + h * 64;
        // epilogue layout: lane owns col q = l31; rows d = (r&3)+8*(r>>2)+4*hi
#pragma unroll
        for (int t = 0; t < 4; ++t) {
            bf16x4 p0, p1;
#pragma unroll
            for (int i = 0; i < 4; ++i) {
                p0[i] = (bf16)(o0[4 * t + i] * fa + r[(4 * t + i) * 64 + lane] * fb);
                p1[i] = (bf16)(o1[4 * t + i] * fa + r[1024 + (4 * t + i) * 64 + lane] * fb);
            }
            *(bf16x4*)(dst + 8 * t + 4 * hi) = p0;
            *(bf16x4*)(dst + 32 + 8 * t + 4 * hi) = p1;
        }
    }
}

// ---------------- launch ----------------
extern "C" void kernel_launch(void* const* d_in, const int* in_sizes, int n_in,
                              void* d_out, int out_size, void* d_ws, size_t ws_size,
                              hipStream_t stream) {
    (void)in_sizes; (void)n_in; (void)out_size; (void)ws_size;
    const float* x    = (const float*)d_in[0];
    const float* Wqkv = (const float*)d_in[1];
    const float* bqkv = (const float*)d_in[2];
    const float* Wout = (const float*)d_in[3];
    const float* bout = (const float*)d_in[4];
    float* out = (float*)d_out;
    char* ws = (char*)d_ws;

    bf16* xbf    = (bf16*)(ws + OFF_XATT);
    bf16* att    = (bf16*)(ws + OFF_XATT);   // aliases xbf (dead after gemm_qkv)
    bf16* wqkvT  = (bf16*)(ws + OFF_WQKVT);
    bf16* woutT  = (bf16*)(ws + OFF_WOUTT);
    float2* tab  = (float2*)(ws + OFF_TAB);
    bf16* qb     = (bf16*)(ws + OFF_Q);
    bf16* kb     = (bf16*)(ws + OFF_K);
    bf16* vt     = (bf16*)(ws + OFF_VT);

    (void)hipFuncSetAttribute((const void*)k_gemm_qkv256,
                              hipFuncAttributeMaxDynamicSharedMemorySize, 131072);

    hipLaunchKernelGGL(k_prep, dim3(NB_CONV + NB_TQ + NB_TO + NB_SC), dim3(256), 0, stream,
                       x, Wqkv, Wout, xbf, wqkvT, woutT, tab);
    hipLaunchKernelGGL(k_gemm_qkv256, dim3(192), dim3(512), 131072, stream,
                       xbf, wqkvT, bqkv, qb, kb, vt, tab);
    hipLaunchKernelGGL(k_attn, dim3(32 * 16), dim3(512), 0, stream, qb, kb, vt, att);
    hipLaunchKernelGGL(k_gemm_out, dim3((Dm / 128) * (BL / 128)), dim3(256), 0, stream,
                       att, woutT, bout, out);
}

// Round 17
// 119.312 us; speedup vs baseline: 1.0319x; 1.0049x over previous
//
#include <hip/hip_runtime.h>
#include <hip/hip_bf16.h>
#include <math.h>

typedef __bf16 bf16;
typedef __bf16 bf16x8 __attribute__((ext_vector_type(8)));
typedef __bf16 bf16x4 __attribute__((ext_vector_type(4)));
typedef __bf16 bf16x2 __attribute__((ext_vector_type(2)));
typedef float f32x4 __attribute__((ext_vector_type(4)));
typedef float f32x16 __attribute__((ext_vector_type(16)));

#define DEV __device__ __forceinline__
#define AS1(p) ((const __attribute__((address_space(1))) void*)(p))
#define AS3(p) ((__attribute__((address_space(3))) void*)(p))

// ---------------- problem sizes ----------------
#define Bsz 2
#define Lseq 2048
#define Dm 1024
#define Hh 16
#define HD 64
#define BL (Bsz * Lseq)   // 4096 rows
#define TN (3 * Dm)       // 3072

#define LOG2E 1.44269504088896f

// ---------------- workspace layout (bytes) ----------------
#define OFF_XATT  ((size_t)0)                            // xbf bf16 8.39MB; att aliases after gemm1
#define OFF_WQKVT (OFF_XATT  + (size_t)BL * Dm * 2)      // 6.29MB
#define OFF_WOUTT (OFF_WQKVT + (size_t)TN * Dm * 2)      // 2.10MB
#define OFF_TAB   (OFF_WOUTT + (size_t)Dm * Dm * 2)      // 0.52MB
#define OFF_Q     (OFF_TAB   + (size_t)Lseq * 32 * 8)    // 8.39MB q bf16 [32][2048][64]
#define OFF_K     (OFF_Q     + (size_t)BL * Dm * 2)      // 8.39MB
#define OFF_VT    (OFF_K     + (size_t)BL * Dm * 2)      // 8.39MB vT bf16 [32][64][2048]
// end = 42.5 MB

DEV float exp2_fast(float x) {   // 2^x, single v_exp_f32
    float r;
    asm("v_exp_f32 %0, %1" : "=v"(r) : "v"(x));
    return r;
}
// v_permlane32_swap_b32 a,b: a_new[32..63]=b_old[0..31], b_new[0..31]=a_old[32..63].
// ONLY safe when a and b occupy DISTINCT registers (R9 post-mortem:
// identical-valued operands got register-coalesced -> self-swap garbage).
// R11: no hand-written pk/max3 asm trees (operand-marshal movs regressed).
// R14: fixed-shift (max-free) softmax FAILED validation -- keep running max.
DEV void plswap(unsigned& a, unsigned& b) {
    asm("v_permlane32_swap_b32 %0, %1" : "+v"(a), "+v"(b));
}
// cross-half (lane ^ 32) value fetch without DS: forced-distinct copy via
// early-clobber v_mov (output reg guaranteed != input; both vregs then live
// AND written at the swap, so the allocator cannot coalesce them), then
// permlane32_swap. Lane l<32 ends with {x[l], x[l+32]}, lane l>=32 with
// {x[l-32], x[l]} -- op(a,b) = pairwise reduce in every lane.
DEV void xhalf_pair(float x, float& a, float& b) {
    float y;
    asm("v_mov_b32 %0, %1" : "=&v"(y) : "v"(x));
    asm("v_permlane32_swap_b32 %0, %1" : "+v"(x), "+v"(y));
    a = x; b = y;
}

// ---------------- fused prep: convert + 2 transposes + sincos table --------
// R11 win (-8.8us): one kernel, 4 block-ranges, stages run concurrently.
#define NB_CONV 2048              // (BL*Dm/8)/256
#define NB_TQ   3072              // (TN/32)*(Dm/32)
#define NB_TO   1024              // (Dm/32)*(Dm/32)
#define NB_SC   256               // Lseq*32/256
__global__ __launch_bounds__(256) void k_prep(const float* __restrict__ x,
                                              const float* __restrict__ Wqkv,
                                              const float* __restrict__ Wout,
                                              bf16* __restrict__ xbf,
                                              bf16* __restrict__ wqkvT,
                                              bf16* __restrict__ woutT,
                                              float2* __restrict__ tab) {
    const int bb = blockIdx.x;
    const int tid = threadIdx.x;
    if (bb < NB_CONV) {
        int i = bb * 256 + tid;
        const float4* in4 = (const float4*)x;
        float4 a = in4[i * 2], b = in4[i * 2 + 1];
        bf16x8 o;
        o[0] = (bf16)a.x; o[1] = (bf16)a.y; o[2] = (bf16)a.z; o[3] = (bf16)a.w;
        o[4] = (bf16)b.x; o[5] = (bf16)b.y; o[6] = (bf16)b.z; o[7] = (bf16)b.w;
        ((bf16x8*)xbf)[i] = o;
    } else if (bb < NB_CONV + NB_TQ + NB_TO) {
        const bool isQ = bb < NB_CONV + NB_TQ;
        const int lb = isQ ? bb - NB_CONV : bb - (NB_CONV + NB_TQ);
        const int nx = isQ ? (TN / 32) : (Dm / 32);
        const int C = isQ ? TN : Dm;           // R = Dm for both
        const float* in = isQ ? Wqkv : Wout;
        bf16* out = isQ ? wqkvT : woutT;
        __shared__ float t[32][33];
        const int bx = (lb % nx) * 32, by = (lb / nx) * 32;
        const int tx = tid & 31, ty = tid >> 5;
#pragma unroll
        for (int i = 0; i < 32; i += 8)
            t[ty + i][tx] = in[(size_t)(by + ty + i) * C + bx + tx];
        __syncthreads();
#pragma unroll
        for (int i = 0; i < 32; i += 8)
            out[(size_t)(bx + ty + i) * Dm + by + tx] = (bf16)t[tx][ty + i];
    } else {
        int idx = (bb - (NB_CONV + NB_TQ + NB_TO)) * 256 + tid;
        int pos = idx >> 5, tt = idx & 31;
        float theta = powf(10000.0f, -(float)tt * (1.0f / 32.0f));
        float f = (float)pos * theta;
        tab[idx] = make_float2(sinf(f), cosf(f));
    }
}

DEV f32x4 mfma16(bf16x8 a, bf16x8 b, f32x4 c) {
    return __builtin_amdgcn_mfma_f32_16x16x32_bf16(a, b, c, 0, 0, 0);
}

// ------------- 256x256 QKV GEMM, 8 waves, dbuf 128KB dynamic LDS (R13 win) -
__global__ __launch_bounds__(512, 2) void k_gemm_qkv256(
        const bf16* __restrict__ A, const bf16* __restrict__ BT,
        const float* __restrict__ bias,
        bf16* __restrict__ qo, bf16* __restrict__ ko, bf16* __restrict__ vt,
        const float2* __restrict__ tab) {
    extern __shared__ char dynlds[];   // 131072 B: buf[2] x (A 32KB | B 32KB)
    const int tid = threadIdx.x;
    const int wid = tid >> 6, lane = tid & 63;
    const int lg = lane >> 4, lr = lane & 15;
    const int wr = wid >> 2, wc = wid & 3;     // wave = (wr 0..1) x (wc 0..3)
    const int id = blockIdx.x;
    const int id2 = (id & 7) * 24 + (id >> 3);
    const int n0 = (id2 % 12) * 256;
    const int m0 = (id2 / 12) * 256;
    const char* Ab = (const char*)A;
    const char* Bb = (const char*)BT;
    const size_t Kb = (size_t)Dm * 2;

    f32x4 acc[8][4] = {};

    const int rowL = lane >> 3;
    const int j16 = ((lane & 7) ^ rowL) * 16;  // pre-swizzled source chunk

    auto STAGE = [&](char* buf, int kt) {
        char* Al = buf;
        char* Bl = buf + 32768;
#pragma unroll
        for (int c = 0; c < 4; ++c) {
            const int g = wid * 4 + c;         // 8-row group 0..31
            const int row = g * 8 + rowL;
            __builtin_amdgcn_global_load_lds(
                AS1(Ab + (size_t)(m0 + row) * Kb + kt * 128 + j16),
                AS3(Al + g * 1024), 16, 0, 0);
            __builtin_amdgcn_global_load_lds(
                AS1(Bb + (size_t)(n0 + row) * Kb + kt * 128 + j16),
                AS3(Bl + g * 1024), 16, 0, 0);
        }
    };
    auto COMPUTE = [&](const char* buf) {
        const char* Al = buf + wr * 16384;
        const char* Bl = buf + 32768 + wc * 8192;
        __builtin_amdgcn_s_setprio(1);
#pragma unroll
        for (int kf = 0; kf < 2; ++kf) {
            bf16x8 af[8], bfr[4];
#pragma unroll
            for (int i = 0; i < 8; ++i) {
                const int ra = i * 16 + lr;
                af[i] = *(const bf16x8*)(Al + ra * 128 + ((kf * 64 + lg * 16) ^ ((ra & 7) << 4)));
            }
#pragma unroll
            for (int j = 0; j < 4; ++j) {
                const int rb = j * 16 + lr;
                bfr[j] = *(const bf16x8*)(Bl + rb * 128 + ((kf * 64 + lg * 16) ^ ((rb & 7) << 4)));
            }
#pragma unroll
            for (int i = 0; i < 8; ++i)
#pragma unroll
                for (int j = 0; j < 4; ++j)
                    acc[i][j] = mfma16(af[i], bfr[j], acc[i][j]);
        }
        __builtin_amdgcn_s_setprio(0);
    };

    STAGE(dynlds, 0);
    __syncthreads();
#pragma unroll 1
    for (int t = 0; t < 16; ++t) {
        char* cur = dynlds + (size_t)(t & 1) * 65536;
        if (t < 15) STAGE(dynlds + (size_t)((t & 1) ^ 1) * 65536, t + 1);
        COMPUTE(cur);
        __syncthreads();
    }

    // ---- fused epilogue: RoPE q (scaled 1/8*log2e), RoPE k, transposed vT --
    const int ph = n0 >> 10;                   // 0=q 1=k 2=v (block-uniform)
    const int c0 = n0 + wc * 64;
    const int h = (c0 & 1023) >> 6;
    const int lrow0 = m0 + wr * 128;
    const int b = lrow0 >> 11;
    const int bh = b * 16 + h;
    const int lbase = lrow0 & 2047;
    float bv[4];
#pragma unroll
    for (int j = 0; j < 4; ++j) bv[j] = bias[c0 + j * 16 + lr];
    float* Lw = (float*)(dynlds + wid * 4096);   // per-wave 16x64 fp32 slab

#pragma unroll   // FULL unroll: compile-time acc indices (rule #20)
    for (int i = 0; i < 8; ++i) {
#pragma unroll
        for (int j = 0; j < 4; ++j)
#pragma unroll
            for (int r = 0; r < 4; ++r)
                Lw[(lg * 4 + r) * 64 + j * 16 + lr] = acc[i][j][r] + bv[j];
        __syncthreads();
        if (ph < 2) {
            const float scale = (ph == 0) ? 0.125f * LOG2E : 1.0f;
            bf16* dst = (ph == 0 ? qo : ko) + (size_t)bh * Lseq * 64;
#pragma unroll
            for (int j = 0; j < 4; ++j)
#pragma unroll
                for (int r = 0; r < 4; ++r) {
                    int rl = lg * 4 + r;
                    int d = j * 16 + lr;
                    int l = lbase + i * 16 + rl;
                    float v = Lw[rl * 64 + d];
                    int dp = (d < 32) ? (2 * d + 1) : (2 * d - 64);
                    float p = Lw[rl * 64 + dp];
                    float2 f = tab[l * 32 + (d & 31)];
                    float val = ((d < 32) ? (v - p) * f.x : (v + p) * f.y) * scale;
                    dst[(size_t)l * 64 + d] = (bf16)val;
                }
        } else {
            int d = lane;
            int lb = lbase + i * 16;
            bf16x8 o1, o2;
#pragma unroll
            for (int rw = 0; rw < 8; ++rw) {
                o1[rw] = (bf16)Lw[rw * 64 + d];
                o2[rw] = (bf16)Lw[(rw + 8) * 64 + d];
            }
            bf16* dst = vt + ((size_t)bh * 64 + d) * Lseq + lb;
            *(bf16x8*)dst = o1;
            *(bf16x8*)(dst + 8) = o2;
        }
        __syncthreads();
    }
}

// ---------------- bf16 GEMM, 128x128 tile, BK=64 (output projection) -------
__global__ __launch_bounds__(256) void k_gemm_out(const bf16* __restrict__ A,
                                                  const bf16* __restrict__ BT,
                                                  const float* __restrict__ bias,
                                                  float* __restrict__ C) {
    __shared__ uint4 smem4[2048];   // 32KB: A tile 16KB + B tile 16KB
    char* Al = (char*)smem4;
    char* Bl = (char*)smem4 + 16384;
    const int tid = threadIdx.x;
    const int w = tid >> 6, lane = tid & 63, lg = lane >> 4, lr = lane & 15;
    const int id = blockIdx.x;
    const int id2 = (id & 7) * 32 + (id >> 3);    // 256 blocks, 32/XCD
    const int n0 = (id2 & 7) * 128;               // Dm/128 = 8
    const int m0 = (id2 >> 3) * 128;
    const int wm = (w >> 1) * 64, wn = (w & 1) * 64;
    const char* Ab = (const char*)A;
    const char* Bb = (const char*)BT;
    const size_t Kb = (size_t)Dm * 2;

    f32x4 acc[4][4] = {};

    const int rowL = lane >> 3;
    const int j16 = ((lane & 7) ^ rowL) * 16;

    for (int kt = 0; kt < Dm; kt += 64) {
#pragma unroll
        for (int c = 0; c < 4; ++c) {
            const int R0 = (w * 4 + c) * 8;
            const int row = R0 + rowL;
            __builtin_amdgcn_global_load_lds(AS1(Ab + (size_t)(m0 + row) * Kb + kt * 2 + j16),
                                             AS3(Al + R0 * 128), 16, 0, 0);
            __builtin_amdgcn_global_load_lds(AS1(Bb + (size_t)(n0 + row) * Kb + kt * 2 + j16),
                                             AS3(Bl + R0 * 128), 16, 0, 0);
        }
        __syncthreads();
#pragma unroll
        for (int kf = 0; kf < 2; ++kf) {
            bf16x8 af[4], bfr[4];
#pragma unroll
            for (int i = 0; i < 4; ++i) {
                int ra = wm + i * 16 + lr;
                af[i] = *(const bf16x8*)(Al + ra * 128 + ((kf * 64 + lg * 16) ^ ((ra & 7) << 4)));
                int rb = wn + i * 16 + lr;
                bfr[i] = *(const bf16x8*)(Bl + rb * 128 + ((kf * 64 + lg * 16) ^ ((rb & 7) << 4)));
            }
#pragma unroll
            for (int i = 0; i < 4; ++i)
#pragma unroll
                for (int j = 0; j < 4; ++j)
                    acc[i][j] = mfma16(af[i], bfr[j], acc[i][j]);
        }
        __syncthreads();
    }

#pragma unroll
    for (int i = 0; i < 4; ++i) {
        int row = m0 + wm + i * 16 + lg * 4;
#pragma unroll
        for (int j = 0; j < 4; ++j) {
            int col = n0 + wn + j * 16 + lr;
            float bv = bias[col];
#pragma unroll
            for (int r = 0; r < 4; ++r)
                C[(size_t)(row + r) * Dm + col] = acc[i][j][r] + bv;
        }
    }
}

// ---------------- stage 3: flash attention (swapped-operand, 32x32x16) ------
// R17 = R16 body with the two cross-half __shfl_xor(,32) reductions replaced
// by permlane32_swap + forced-distinct copy (no DS round-trip on the softmax
// critical path). Everything else unchanged.
DEV f32x16 mfma32(bf16x8 a, bf16x8 b, f32x16 c) {
    return __builtin_amdgcn_mfma_f32_32x32x16_bf16(a, b, c, 0, 0, 0);
}
DEV unsigned packbf(float lo, float hi) {
    bf16x2 v;
    v[0] = (bf16)lo;
    v[1] = (bf16)hi;
    return __builtin_bit_cast(unsigned, v);   // little-endian: v[0] = low 16b
}

DEV void stage_k(const char* kb, char* dst, int j0, int qw, int lane) {
#pragma unroll
    for (int c = 0; c < 2; ++c) {
        const int j = qw * 2 + c;              // chunk 0..7 (wave-uniform)
        const int rsw = lane ^ j;              // pre-swizzled source row
        __builtin_amdgcn_global_load_lds(AS1(kb + (size_t)(j0 + rsw) * 128 + j * 16),
                                         AS3(dst + j * 1024), 16, 0, 0);
    }
}
DEV void stage_v(const char* vb, char* dst, int j0, int qw, int lane) {
#pragma unroll
    for (int c = 0; c < 2; ++c) {
        const int j = qw * 2 + c;
        const int rsw = lane ^ j;
        __builtin_amdgcn_global_load_lds(AS1(vb + (size_t)rsw * 4096 + (size_t)j0 * 2 + j * 16),
                                         AS3(dst + j * 1024), 16, 0, 0);
    }
}

__global__ __launch_bounds__(512, 4) void k_attn(const bf16* __restrict__ Q,
                                                 const bf16* __restrict__ Kt,
                                                 const bf16* __restrict__ Vt,
                                                 bf16* __restrict__ Op) {
    __shared__ uint4 smem4[4096];   // 64KB: 2 halves x (2 bufs x [K 8K | V 8K])
    char* base = (char*)smem4;
    const int tid = threadIdx.x;
    const int w = tid >> 6, lane = tid & 63;
    const int qw = w & 3, s = w >> 2;
    const int hi = lane >> 5, l31 = lane & 31;
    const int bid = blockIdx.x;
    const int bh = bid >> 4, qt = bid & 15;
    const int q0 = qt * 128 + qw * 32;
    const char* qb = (const char*)(Q + (size_t)bh * Lseq * 64);
    const char* kb = (const char*)(Kt + (size_t)bh * Lseq * 64);
    const char* vb = (const char*)(Vt + (size_t)bh * 64 * Lseq);
    char* setb = base + s * 32768;             // this half's pipeline
    const int jbase = s * 16;                  // this half's first tile index

    // Q frags (B-operand): elem i = Q[q0+l31][kst*16 + hi*8 + i]
    bf16x8 qf[4];
#pragma unroll
    for (int kst = 0; kst < 4; ++kst)
        qf[kst] = *(const bf16x8*)(qb + (size_t)(q0 + l31) * 128 + kst * 32 + hi * 16);

    f32x16 o0 = {}, o1 = {};
    float m = -1e30f, lsum = 0.f;

    // prologue: stage tile 0 of this half into buf 0
    stage_k(kb, setb, jbase * 64, qw, lane);
    stage_v(vb, setb + 8192, jbase * 64, qw, lane);
    __syncthreads();

    for (int t = 0; t < 16; ++t) {
        const int cur = t & 1;
        const char* Kl = setb + cur * 16384;
        const char* Vl = Kl + 8192;
        char* Kn = setb + (cur ^ 1) * 16384;
        char* Vn = Kn + 8192;

        // async-stage next tile (drains at this iteration's end barrier)
        if (t < 15) {
            stage_k(kb, Kn, (jbase + t + 1) * 64, qw, lane);
            stage_v(vb, Vn, (jbase + t + 1) * 64, qw, lane);
        }

        // S^T = K * Q^T : s0 = j rows 0..31, s1 = 32..63 (col q = l31)
        f32x16 s0 = {}, s1 = {};
        __builtin_amdgcn_s_setprio(1);
#pragma unroll
        for (int kst = 0; kst < 4; ++kst) {
            const int jK = kst * 2 + hi;
            const int x = l31 ^ jK;            // jK<8: flips low 3 bits only
            bf16x8 ka = *(const bf16x8*)(Kl + jK * 1024 + x * 16);
            bf16x8 kc = *(const bf16x8*)(Kl + jK * 1024 + (32 + x) * 16);
            s0 = mfma32(ka, qf[kst], s0);
            s1 = mfma32(kc, qf[kst], s1);
        }
        __builtin_amdgcn_s_setprio(0);

        // row-max: 4 independent chains (depth 7) + combine (depth 2)
        float cA = s0[0], cB = s0[8], cC = s1[0], cD = s1[8];
#pragma unroll
        for (int r = 1; r < 8; ++r) {
            cA = fmaxf(cA, s0[r]);
            cB = fmaxf(cB, s0[8 + r]);
            cC = fmaxf(cC, s1[r]);
            cD = fmaxf(cD, s1[8 + r]);
        }
        float pm = fmaxf(fmaxf(cA, cB), fmaxf(cC, cD));
        {   // cross-half max via permlane (no DS): see xhalf_pair note
            float a, b;
            xhalf_pair(pm, a, b);
            pm = fmaxf(a, b);
        }
        if (!__all(pm <= m + 8.0f)) {          // defer-max (T13), log2 units
            float mn = fmaxf(m, pm);
            float sc = exp2_fast(m - mn);
#pragma unroll
            for (int r = 0; r < 16; ++r) { o0[r] *= sc; o1[r] *= sc; }
            lsum *= sc; m = mn;
        }
        // exp + row-sum: 4 independent accumulation chains
        float rA = 0.f, rB = 0.f, rC = 0.f, rD = 0.f;
#pragma unroll
        for (int r = 0; r < 8; ++r) {
            s0[r]     = exp2_fast(s0[r] - m);     rA += s0[r];
            s0[8 + r] = exp2_fast(s0[8 + r] - m); rB += s0[8 + r];
            s1[r]     = exp2_fast(s1[r] - m);     rC += s1[r];
            s1[8 + r] = exp2_fast(s1[8 + r] - m); rD += s1[8 + r];
        }
        float rs = (rA + rB) + (rC + rD);
        {   // cross-half sum via permlane (no DS)
            float a, b;
            xhalf_pair(rs, a, b);
            rs = a + b;
        }
        lsum += rs;

        // pack P to bf16 pairs (cvt_pk-fusable form); cross-half exchange =
        // 8 in-place permlane swaps on DISTINCT-valued register pairs
        unsigned u[16];
#pragma unroll
        for (int t2 = 0; t2 < 8; ++t2) {
            u[t2]     = packbf(s0[2 * t2], s0[2 * t2 + 1]);
            u[8 + t2] = packbf(s1[2 * t2], s1[2 * t2 + 1]);
        }
        bf16x8 pf[2][2];
#pragma unroll
        for (int J = 0; J < 2; ++J)
#pragma unroll
            for (int st = 0; st < 2; ++st) {
                const int t0 = J * 8 + st * 4;
                plswap(u[t0 + 0], u[t0 + 2]);
                plswap(u[t0 + 1], u[t0 + 3]);
                union { unsigned wd[4]; bf16x8 v; } f;
                f.wd[0] = u[t0 + 0];
                f.wd[1] = u[t0 + 1];
                f.wd[2] = u[t0 + 2];
                f.wd[3] = u[t0 + 3];
                pf[J][st] = f.v;
            }

        // O^T += V^T * P^T : o0 = d rows 0..31, o1 = 32..63 (col q = l31)
        __builtin_amdgcn_s_setprio(1);
#pragma unroll
        for (int J = 0; J < 2; ++J)
#pragma unroll
            for (int st = 0; st < 2; ++st) {
                const int jV = J * 4 + st * 2 + hi;
                const int x = l31 ^ jV;
                bf16x8 v0 = *(const bf16x8*)(Vl + jV * 1024 + x * 16);
                bf16x8 v1 = *(const bf16x8*)(Vl + jV * 1024 + (32 + x) * 16);
                o0 = mfma32(v0, pf[J][st], o0);
                o1 = mfma32(v1, pf[J][st], o1);
            }
        __builtin_amdgcn_s_setprio(0);
        __syncthreads();
    }

    // ---- combine the two KV halves (LDS exchange; K/V buffers now dead) ----
    float* ex = (float*)base;                   // per qw-wave region: 2176 floats
    if (s == 1) {
        float* r = ex + qw * 2176;
#pragma unroll
        for (int t = 0; t < 16; ++t) {
            r[t * 64 + lane] = o0[t];
            r[1024 + t * 64 + lane] = o1[t];
        }
        r[2048 + lane] = m;
        r[2112 + lane] = lsum;
    }
    __syncthreads();
    if (s == 0) {
        float* r = ex + qw * 2176;
        const float mb = r[2048 + lane], lb = r[2112 + lane];
        const float M = fmaxf(m, mb);
        const float wa = exp2_fast(m - M), wb = exp2_fast(mb - M);
        const float inv = 1.0f / (wa * lsum + wb * lb);
        const float fa = wa * inv, fb = wb * inv;
        const int b = bh >> 4, h = bh & 15;
        bf16* dst = Op + (size_t)(b * Lseq + q0 + l31) * Dm + h * 64;
        // epilogue layout: lane owns col q = l31; rows d = (r&3)+8*(r>>2)+4*hi
#pragma unroll
        for (int t = 0; t < 4; ++t) {
            bf16x4 p0, p1;
#pragma unroll
            for (int i = 0; i < 4; ++i) {
                p0[i] = (bf16)(o0[4 * t + i] * fa + r[(4 * t + i) * 64 + lane] * fb);
                p1[i] = (bf16)(o1[4 * t + i] * fa + r[1024 + (4 * t + i) * 64 + lane] * fb);
            }
            *(bf16x4*)(dst + 8 * t + 4 * hi) = p0;
            *(bf16x4*)(dst + 32 + 8 * t + 4 * hi) = p1;
        }
    }
}

// ---------------- launch ----------------
extern "C" void kernel_launch(void* const* d_in, const int* in_sizes, int n_in,
                              void* d_out, int out_size, void* d_ws, size_t ws_size,
                              hipStream_t stream) {
    (void)in_sizes; (void)n_in; (void)out_size; (void)ws_size;
    const float* x    = (const float*)d_in[0];
    const float* Wqkv = (const float*)d_in[1];
    const float* bqkv = (const float*)d_in[2];
    const float* Wout = (const float*)d_in[3];
    const float* bout = (const float*)d_in[4];
    float* out = (float*)d_out;
    char* ws = (char*)d_ws;

    bf16* xbf    = (bf16*)(ws + OFF_XATT);
    bf16* att    = (bf16*)(ws + OFF_XATT);   // aliases xbf (dead after gemm_qkv)
    bf16* wqkvT  = (bf16*)(ws + OFF_WQKVT);
    bf16* woutT  = (bf16*)(ws + OFF_WOUTT);
    float2* tab  = (float2*)(ws + OFF_TAB);
    bf16* qb     = (bf16*)(ws + OFF_Q);
    bf16* kb     = (bf16*)(ws + OFF_K);
    bf16* vt     = (bf16*)(ws + OFF_VT);

    (void)hipFuncSetAttribute((const void*)k_gemm_qkv256,
                              hipFuncAttributeMaxDynamicSharedMemorySize, 131072);

    hipLaunchKernelGGL(k_prep, dim3(NB_CONV + NB_TQ + NB_TO + NB_SC), dim3(256), 0, stream,
                       x, Wqkv, Wout, xbf, wqkvT, woutT, tab);
    hipLaunchKernelGGL(k_gemm_qkv256, dim3(192), dim3(512), 131072, stream,
                       xbf, wqkvT, bqkv, qb, kb, vt, tab);
    hipLaunchKernelGGL(k_attn, dim3(32 * 16), dim3(512), 0, stream, qb, kb, vt, att);
    hipLaunchKernelGGL(k_gemm_out, dim3((Dm / 128) * (BL / 128)), dim3(256), 0, stream,
                       att, woutT, bout, out);
}

// Round 18
// 115.622 us; speedup vs baseline: 1.0648x; 1.0319x over previous
//
#include <hip/hip_runtime.h>
#include <hip/hip_bf16.h>
#include <math.h>

typedef __bf16 bf16;
typedef __bf16 bf16x8 __attribute__((ext_vector_type(8)));
typedef __bf16 bf16x4 __attribute__((ext_vector_type(4)));
typedef __bf16 bf16x2 __attribute__((ext_vector_type(2)));
typedef float f32x4 __attribute__((ext_vector_type(4)));
typedef float f32x16 __attribute__((ext_vector_type(16)));

#define DEV __device__ __forceinline__
#define AS1(p) ((const __attribute__((address_space(1))) void*)(p))
#define AS3(p) ((__attribute__((address_space(3))) void*)(p))

// ---------------- problem sizes ----------------
#define Bsz 2
#define Lseq 2048
#define Dm 1024
#define Hh 16
#define HD 64
#define BL (Bsz * Lseq)   // 4096 rows
#define TN (3 * Dm)       // 3072

#define LOG2E 1.44269504088896f

// ---------------- workspace layout (bytes) ----------------
#define OFF_XATT  ((size_t)0)                            // xbf bf16 8.39MB; att aliases after gemm1
#define OFF_WQKVT (OFF_XATT  + (size_t)BL * Dm * 2)      // 6.29MB
#define OFF_WOUTT (OFF_WQKVT + (size_t)TN * Dm * 2)      // 2.10MB
#define OFF_TAB   (OFF_WOUTT + (size_t)Dm * Dm * 2)      // 0.52MB
#define OFF_Q     (OFF_TAB   + (size_t)Lseq * 32 * 8)    // 8.39MB q bf16 [32][2048][64]
#define OFF_K     (OFF_Q     + (size_t)BL * Dm * 2)      // 8.39MB
#define OFF_VT    (OFF_K     + (size_t)BL * Dm * 2)      // 8.39MB vT bf16 [32][64][2048]
// end = 42.5 MB

DEV float exp2_fast(float x) {   // 2^x, single v_exp_f32
    float r;
    asm("v_exp_f32 %0, %1" : "=v"(r) : "v"(x));
    return r;
}
// v_permlane32_swap_b32 a,b: a_new[32..63]=b_old[0..31], b_new[0..31]=a_old[32..63].
// ONLY safe when a and b occupy DISTINCT registers (R9 post-mortem).
// R11: no hand-written pk/max3 asm trees. R14: fixed-shift softmax FAILED.
DEV void plswap(unsigned& a, unsigned& b) {
    asm("v_permlane32_swap_b32 %0, %1" : "+v"(a), "+v"(b));
}
// cross-half (lane ^ 32) pair fetch without DS (forced-distinct copy).
DEV void xhalf_pair(float x, float& a, float& b) {
    float y;
    asm("v_mov_b32 %0, %1" : "=&v"(y) : "v"(x));
    asm("v_permlane32_swap_b32 %0, %1" : "+v"(x), "+v"(y));
    a = x; b = y;
}

// ---------------- fused prep: convert + 2 transposes + sincos table --------
#define NB_CONV 2048              // (BL*Dm/8)/256
#define NB_TQ   3072              // (TN/32)*(Dm/32)
#define NB_TO   1024              // (Dm/32)*(Dm/32)
#define NB_SC   256               // Lseq*32/256
__global__ __launch_bounds__(256) void k_prep(const float* __restrict__ x,
                                              const float* __restrict__ Wqkv,
                                              const float* __restrict__ Wout,
                                              bf16* __restrict__ xbf,
                                              bf16* __restrict__ wqkvT,
                                              bf16* __restrict__ woutT,
                                              float2* __restrict__ tab) {
    const int bb = blockIdx.x;
    const int tid = threadIdx.x;
    if (bb < NB_CONV) {
        int i = bb * 256 + tid;
        const float4* in4 = (const float4*)x;
        float4 a = in4[i * 2], b = in4[i * 2 + 1];
        bf16x8 o;
        o[0] = (bf16)a.x; o[1] = (bf16)a.y; o[2] = (bf16)a.z; o[3] = (bf16)a.w;
        o[4] = (bf16)b.x; o[5] = (bf16)b.y; o[6] = (bf16)b.z; o[7] = (bf16)b.w;
        ((bf16x8*)xbf)[i] = o;
    } else if (bb < NB_CONV + NB_TQ + NB_TO) {
        const bool isQ = bb < NB_CONV + NB_TQ;
        const int lb = isQ ? bb - NB_CONV : bb - (NB_CONV + NB_TQ);
        const int nx = isQ ? (TN / 32) : (Dm / 32);
        const int C = isQ ? TN : Dm;           // R = Dm for both
        const float* in = isQ ? Wqkv : Wout;
        bf16* out = isQ ? wqkvT : woutT;
        __shared__ float t[32][33];
        const int bx = (lb % nx) * 32, by = (lb / nx) * 32;
        const int tx = tid & 31, ty = tid >> 5;
#pragma unroll
        for (int i = 0; i < 32; i += 8)
            t[ty + i][tx] = in[(size_t)(by + ty + i) * C + bx + tx];
        __syncthreads();
#pragma unroll
        for (int i = 0; i < 32; i += 8)
            out[(size_t)(bx + ty + i) * Dm + by + tx] = (bf16)t[tx][ty + i];
    } else {
        int idx = (bb - (NB_CONV + NB_TQ + NB_TO)) * 256 + tid;
        int pos = idx >> 5, tt = idx & 31;
        float theta = powf(10000.0f, -(float)tt * (1.0f / 32.0f));
        float f = (float)pos * theta;
        tab[idx] = make_float2(sinf(f), cosf(f));
    }
}

DEV f32x4 mfma16(bf16x8 a, bf16x8 b, f32x4 c) {
    return __builtin_amdgcn_mfma_f32_16x16x32_bf16(a, b, c, 0, 0, 0);
}

// ------------- 256x256 QKV GEMM, 8 waves, dbuf 128KB dynamic LDS (R13 win) -
__global__ __launch_bounds__(512, 2) void k_gemm_qkv256(
        const bf16* __restrict__ A, const bf16* __restrict__ BT,
        const float* __restrict__ bias,
        bf16* __restrict__ qo, bf16* __restrict__ ko, bf16* __restrict__ vt,
        const float2* __restrict__ tab) {
    extern __shared__ char dynlds[];   // 131072 B: buf[2] x (A 32KB | B 32KB)
    const int tid = threadIdx.x;
    const int wid = tid >> 6, lane = tid & 63;
    const int lg = lane >> 4, lr = lane & 15;
    const int wr = wid >> 2, wc = wid & 3;     // wave = (wr 0..1) x (wc 0..3)
    const int id = blockIdx.x;
    const int id2 = (id & 7) * 24 + (id >> 3);
    const int n0 = (id2 % 12) * 256;
    const int m0 = (id2 / 12) * 256;
    const char* Ab = (const char*)A;
    const char* Bb = (const char*)BT;
    const size_t Kb = (size_t)Dm * 2;

    f32x4 acc[8][4] = {};

    const int rowL = lane >> 3;
    const int j16 = ((lane & 7) ^ rowL) * 16;  // pre-swizzled source chunk

    auto STAGE = [&](char* buf, int kt) {
        char* Al = buf;
        char* Bl = buf + 32768;
#pragma unroll
        for (int c = 0; c < 4; ++c) {
            const int g = wid * 4 + c;         // 8-row group 0..31
            const int row = g * 8 + rowL;
            __builtin_amdgcn_global_load_lds(
                AS1(Ab + (size_t)(m0 + row) * Kb + kt * 128 + j16),
                AS3(Al + g * 1024), 16, 0, 0);
            __builtin_amdgcn_global_load_lds(
                AS1(Bb + (size_t)(n0 + row) * Kb + kt * 128 + j16),
                AS3(Bl + g * 1024), 16, 0, 0);
        }
    };
    auto COMPUTE = [&](const char* buf) {
        const char* Al = buf + wr * 16384;
        const char* Bl = buf + 32768 + wc * 8192;
        __builtin_amdgcn_s_setprio(1);
#pragma unroll
        for (int kf = 0; kf < 2; ++kf) {
            bf16x8 af[8], bfr[4];
#pragma unroll
            for (int i = 0; i < 8; ++i) {
                const int ra = i * 16 + lr;
                af[i] = *(const bf16x8*)(Al + ra * 128 + ((kf * 64 + lg * 16) ^ ((ra & 7) << 4)));
            }
#pragma unroll
            for (int j = 0; j < 4; ++j) {
                const int rb = j * 16 + lr;
                bfr[j] = *(const bf16x8*)(Bl + rb * 128 + ((kf * 64 + lg * 16) ^ ((rb & 7) << 4)));
            }
#pragma unroll
            for (int i = 0; i < 8; ++i)
#pragma unroll
                for (int j = 0; j < 4; ++j)
                    acc[i][j] = mfma16(af[i], bfr[j], acc[i][j]);
        }
        __builtin_amdgcn_s_setprio(0);
    };

    STAGE(dynlds, 0);
    __syncthreads();
#pragma unroll 1
    for (int t = 0; t < 16; ++t) {
        char* cur = dynlds + (size_t)(t & 1) * 65536;
        if (t < 15) STAGE(dynlds + (size_t)((t & 1) ^ 1) * 65536, t + 1);
        COMPUTE(cur);
        __syncthreads();
    }

    // ---- fused epilogue: RoPE q (scaled 1/8*log2e), RoPE k, transposed vT --
    const int ph = n0 >> 10;                   // 0=q 1=k 2=v (block-uniform)
    const int c0 = n0 + wc * 64;
    const int h = (c0 & 1023) >> 6;
    const int lrow0 = m0 + wr * 128;
    const int b = lrow0 >> 11;
    const int bh = b * 16 + h;
    const int lbase = lrow0 & 2047;
    float bv[4];
#pragma unroll
    for (int j = 0; j < 4; ++j) bv[j] = bias[c0 + j * 16 + lr];
    float* Lw = (float*)(dynlds + wid * 4096);   // per-wave 16x64 fp32 slab

#pragma unroll   // FULL unroll: compile-time acc indices (rule #20)
    for (int i = 0; i < 8; ++i) {
#pragma unroll
        for (int j = 0; j < 4; ++j)
#pragma unroll
            for (int r = 0; r < 4; ++r)
                Lw[(lg * 4 + r) * 64 + j * 16 + lr] = acc[i][j][r] + bv[j];
        __syncthreads();
        if (ph < 2) {
            const float scale = (ph == 0) ? 0.125f * LOG2E : 1.0f;
            bf16* dst = (ph == 0 ? qo : ko) + (size_t)bh * Lseq * 64;
#pragma unroll
            for (int j = 0; j < 4; ++j)
#pragma unroll
                for (int r = 0; r < 4; ++r) {
                    int rl = lg * 4 + r;
                    int d = j * 16 + lr;
                    int l = lbase + i * 16 + rl;
                    float v = Lw[rl * 64 + d];
                    int dp = (d < 32) ? (2 * d + 1) : (2 * d - 64);
                    float p = Lw[rl * 64 + dp];
                    float2 f = tab[l * 32 + (d & 31)];
                    float val = ((d < 32) ? (v - p) * f.x : (v + p) * f.y) * scale;
                    dst[(size_t)l * 64 + d] = (bf16)val;
                }
        } else {
            int d = lane;
            int lb = lbase + i * 16;
            bf16x8 o1, o2;
#pragma unroll
            for (int rw = 0; rw < 8; ++rw) {
                o1[rw] = (bf16)Lw[rw * 64 + d];
                o2[rw] = (bf16)Lw[(rw + 8) * 64 + d];
            }
            bf16* dst = vt + ((size_t)bh * 64 + d) * Lseq + lb;
            *(bf16x8*)dst = o1;
            *(bf16x8*)(dst + 8) = o2;
        }
        __syncthreads();
    }
}

// ------- R18: output GEMM, 64x128 tile, 512 blocks = 2 blocks/CU ----------
// R17 ran 256 blocks on 256 CUs = 1 wave/SIMD (zero latency overlap).
// Halving the M-tile doubles occupancy; same proven template otherwise
// (global_load_lds + rule-#21 swizzle; B re-fetch is L2/L3-resident).
__global__ __launch_bounds__(256) void k_gemm_out(const bf16* __restrict__ A,
                                                  const bf16* __restrict__ BT,
                                                  const float* __restrict__ bias,
                                                  float* __restrict__ C) {
    __shared__ uint4 smem4[1536];   // 24KB: A 64x64 8KB + B 128x64 16KB
    char* Al = (char*)smem4;
    char* Bl = (char*)smem4 + 8192;
    const int tid = threadIdx.x;
    const int w = tid >> 6, lane = tid & 63, lg = lane >> 4, lr = lane & 15;
    const int id = blockIdx.x;
    const int id2 = (id & 7) * 64 + (id >> 3);    // 512 blocks, 64/XCD
    const int n0 = (id2 & 7) * 128;               // Dm/128 = 8
    const int m0 = (id2 >> 3) * 64;               // BL/64 = 64
    const int wm = (w >> 1) * 32, wn = (w & 1) * 64;
    const char* Ab = (const char*)A;
    const char* Bb = (const char*)BT;
    const size_t Kb = (size_t)Dm * 2;

    f32x4 acc[2][4] = {};

    const int rowL = lane >> 3;
    const int j16 = ((lane & 7) ^ rowL) * 16;

    for (int kt = 0; kt < Dm; kt += 64) {
        // stage A (8 groups, 2/thread) and B (16 groups, 4/thread)
#pragma unroll
        for (int c = 0; c < 2; ++c) {
            const int g = w * 2 + c;               // 0..7
            __builtin_amdgcn_global_load_lds(
                AS1(Ab + (size_t)(m0 + g * 8 + rowL) * Kb + kt * 2 + j16),
                AS3(Al + g * 1024), 16, 0, 0);
        }
#pragma unroll
        for (int c = 0; c < 4; ++c) {
            const int g = w * 4 + c;               // 0..15
            __builtin_amdgcn_global_load_lds(
                AS1(Bb + (size_t)(n0 + g * 8 + rowL) * Kb + kt * 2 + j16),
                AS3(Bl + g * 1024), 16, 0, 0);
        }
        __syncthreads();
#pragma unroll
        for (int kf = 0; kf < 2; ++kf) {
            bf16x8 af[2], bfr[4];
#pragma unroll
            for (int i = 0; i < 2; ++i) {
                int ra = wm + i * 16 + lr;
                af[i] = *(const bf16x8*)(Al + ra * 128 + ((kf * 64 + lg * 16) ^ ((ra & 7) << 4)));
            }
#pragma unroll
            for (int j = 0; j < 4; ++j) {
                int rb = wn + j * 16 + lr;
                bfr[j] = *(const bf16x8*)(Bl + rb * 128 + ((kf * 64 + lg * 16) ^ ((rb & 7) << 4)));
            }
#pragma unroll
            for (int i = 0; i < 2; ++i)
#pragma unroll
                for (int j = 0; j < 4; ++j)
                    acc[i][j] = mfma16(af[i], bfr[j], acc[i][j]);
        }
        __syncthreads();
    }

#pragma unroll
    for (int i = 0; i < 2; ++i) {
        int row = m0 + wm + i * 16 + lg * 4;
#pragma unroll
        for (int j = 0; j < 4; ++j) {
            int col = n0 + wn + j * 16 + lr;
            float bv = bias[col];
#pragma unroll
            for (int r = 0; r < 4; ++r)
                C[(size_t)(row + r) * Dm + col] = acc[i][j][r] + bv;
        }
    }
}

// ---------------- stage 3: flash attention (swapped-operand, 32x32x16) ------
// R17 winner body (53.1us): running-max online softmax, chain-split
// reductions, cvt_pk-fusable pack, permlane exchange + permlane reductions.
DEV f32x16 mfma32(bf16x8 a, bf16x8 b, f32x16 c) {
    return __builtin_amdgcn_mfma_f32_32x32x16_bf16(a, b, c, 0, 0, 0);
}
DEV unsigned packbf(float lo, float hi) {
    bf16x2 v;
    v[0] = (bf16)lo;
    v[1] = (bf16)hi;
    return __builtin_bit_cast(unsigned, v);   // little-endian: v[0] = low 16b
}

DEV void stage_k(const char* kb, char* dst, int j0, int qw, int lane) {
#pragma unroll
    for (int c = 0; c < 2; ++c) {
        const int j = qw * 2 + c;              // chunk 0..7 (wave-uniform)
        const int rsw = lane ^ j;              // pre-swizzled source row
        __builtin_amdgcn_global_load_lds(AS1(kb + (size_t)(j0 + rsw) * 128 + j * 16),
                                         AS3(dst + j * 1024), 16, 0, 0);
    }
}
DEV void stage_v(const char* vb, char* dst, int j0, int qw, int lane) {
#pragma unroll
    for (int c = 0; c < 2; ++c) {
        const int j = qw * 2 + c;
        const int rsw = lane ^ j;
        __builtin_amdgcn_global_load_lds(AS1(vb + (size_t)rsw * 4096 + (size_t)j0 * 2 + j * 16),
                                         AS3(dst + j * 1024), 16, 0, 0);
    }
}

__global__ __launch_bounds__(512, 4) void k_attn(const bf16* __restrict__ Q,
                                                 const bf16* __restrict__ Kt,
                                                 const bf16* __restrict__ Vt,
                                                 bf16* __restrict__ Op) {
    __shared__ uint4 smem4[4096];   // 64KB: 2 halves x (2 bufs x [K 8K | V 8K])
    char* base = (char*)smem4;
    const int tid = threadIdx.x;
    const int w = tid >> 6, lane = tid & 63;
    const int qw = w & 3, s = w >> 2;
    const int hi = lane >> 5, l31 = lane & 31;
    const int bid = blockIdx.x;
    const int bh = bid >> 4, qt = bid & 15;
    const int q0 = qt * 128 + qw * 32;
    const char* qb = (const char*)(Q + (size_t)bh * Lseq * 64);
    const char* kb = (const char*)(Kt + (size_t)bh * Lseq * 64);
    const char* vb = (const char*)(Vt + (size_t)bh * 64 * Lseq);
    char* setb = base + s * 32768;             // this half's pipeline
    const int jbase = s * 16;                  // this half's first tile index

    // Q frags (B-operand): elem i = Q[q0+l31][kst*16 + hi*8 + i]
    bf16x8 qf[4];
#pragma unroll
    for (int kst = 0; kst < 4; ++kst)
        qf[kst] = *(const bf16x8*)(qb + (size_t)(q0 + l31) * 128 + kst * 32 + hi * 16);

    f32x16 o0 = {}, o1 = {};
    float m = -1e30f, lsum = 0.f;

    // prologue: stage tile 0 of this half into buf 0
    stage_k(kb, setb, jbase * 64, qw, lane);
    stage_v(vb, setb + 8192, jbase * 64, qw, lane);
    __syncthreads();

    for (int t = 0; t < 16; ++t) {
        const int cur = t & 1;
        const char* Kl = setb + cur * 16384;
        const char* Vl = Kl + 8192;
        char* Kn = setb + (cur ^ 1) * 16384;
        char* Vn = Kn + 8192;

        // async-stage next tile (drains at this iteration's end barrier)
        if (t < 15) {
            stage_k(kb, Kn, (jbase + t + 1) * 64, qw, lane);
            stage_v(vb, Vn, (jbase + t + 1) * 64, qw, lane);
        }

        // S^T = K * Q^T : s0 = j rows 0..31, s1 = 32..63 (col q = l31)
        f32x16 s0 = {}, s1 = {};
        __builtin_amdgcn_s_setprio(1);
#pragma unroll
        for (int kst = 0; kst < 4; ++kst) {
            const int jK = kst * 2 + hi;
            const int x = l31 ^ jK;            // jK<8: flips low 3 bits only
            bf16x8 ka = *(const bf16x8*)(Kl + jK * 1024 + x * 16);
            bf16x8 kc = *(const bf16x8*)(Kl + jK * 1024 + (32 + x) * 16);
            s0 = mfma32(ka, qf[kst], s0);
            s1 = mfma32(kc, qf[kst], s1);
        }
        __builtin_amdgcn_s_setprio(0);

        // row-max: 4 independent chains (depth 7) + combine (depth 2)
        float cA = s0[0], cB = s0[8], cC = s1[0], cD = s1[8];
#pragma unroll
        for (int r = 1; r < 8; ++r) {
            cA = fmaxf(cA, s0[r]);
            cB = fmaxf(cB, s0[8 + r]);
            cC = fmaxf(cC, s1[r]);
            cD = fmaxf(cD, s1[8 + r]);
        }
        float pm = fmaxf(fmaxf(cA, cB), fmaxf(cC, cD));
        {   // cross-half max via permlane (no DS)
            float a, b;
            xhalf_pair(pm, a, b);
            pm = fmaxf(a, b);
        }
        if (!__all(pm <= m + 8.0f)) {          // defer-max (T13), log2 units
            float mn = fmaxf(m, pm);
            float sc = exp2_fast(m - mn);
#pragma unroll
            for (int r = 0; r < 16; ++r) { o0[r] *= sc; o1[r] *= sc; }
            lsum *= sc; m = mn;
        }
        // exp + row-sum: 4 independent accumulation chains
        float rA = 0.f, rB = 0.f, rC = 0.f, rD = 0.f;
#pragma unroll
        for (int r = 0; r < 8; ++r) {
            s0[r]     = exp2_fast(s0[r] - m);     rA += s0[r];
            s0[8 + r] = exp2_fast(s0[8 + r] - m); rB += s0[8 + r];
            s1[r]     = exp2_fast(s1[r] - m);     rC += s1[r];
            s1[8 + r] = exp2_fast(s1[8 + r] - m); rD += s1[8 + r];
        }
        float rs = (rA + rB) + (rC + rD);
        {   // cross-half sum via permlane (no DS)
            float a, b;
            xhalf_pair(rs, a, b);
            rs = a + b;
        }
        lsum += rs;

        // pack P to bf16 pairs (cvt_pk-fusable form); cross-half exchange =
        // 8 in-place permlane swaps on DISTINCT-valued register pairs
        unsigned u[16];
#pragma unroll
        for (int t2 = 0; t2 < 8; ++t2) {
            u[t2]     = packbf(s0[2 * t2], s0[2 * t2 + 1]);
            u[8 + t2] = packbf(s1[2 * t2], s1[2 * t2 + 1]);
        }
        bf16x8 pf[2][2];
#pragma unroll
        for (int J = 0; J < 2; ++J)
#pragma unroll
            for (int st = 0; st < 2; ++st) {
                const int t0 = J * 8 + st * 4;
                plswap(u[t0 + 0], u[t0 + 2]);
                plswap(u[t0 + 1], u[t0 + 3]);
                union { unsigned wd[4]; bf16x8 v; } f;
                f.wd[0] = u[t0 + 0];
                f.wd[1] = u[t0 + 1];
                f.wd[2] = u[t0 + 2];
                f.wd[3] = u[t0 + 3];
                pf[J][st] = f.v;
            }

        // O^T += V^T * P^T : o0 = d rows 0..31, o1 = 32..63 (col q = l31)
        __builtin_amdgcn_s_setprio(1);
#pragma unroll
        for (int J = 0; J < 2; ++J)
#pragma unroll
            for (int st = 0; st < 2; ++st) {
                const int jV = J * 4 + st * 2 + hi;
                const int x = l31 ^ jV;
                bf16x8 v0 = *(const bf16x8*)(Vl + jV * 1024 + x * 16);
                bf16x8 v1 = *(const bf16x8*)(Vl + jV * 1024 + (32 + x) * 16);
                o0 = mfma32(v0, pf[J][st], o0);
                o1 = mfma32(v1, pf[J][st], o1);
            }
        __builtin_amdgcn_s_setprio(0);
        __syncthreads();
    }

    // ---- combine the two KV halves (LDS exchange; K/V buffers now dead) ----
    float* ex = (float*)base;                   // per qw-wave region: 2176 floats
    if (s == 1) {
        float* r = ex + qw * 2176;
#pragma unroll
        for (int t = 0; t < 16; ++t) {
            r[t * 64 + lane] = o0[t];
            r[1024 + t * 64 + lane] = o1[t];
        }
        r[2048 + lane] = m;
        r[2112 + lane] = lsum;
    }
    __syncthreads();
    if (s == 0) {
        float* r = ex + qw * 2176;
        const float mb = r[2048 + lane], lb = r[2112 + lane];
        const float M = fmaxf(m, mb);
        const float wa = exp2_fast(m - M), wb = exp2_fast(mb - M);
        const float inv = 1.0f / (wa * lsum + wb * lb);
        const float fa = wa * inv, fb = wb * inv;
        const int b = bh >> 4, h = bh & 15;
        bf16* dst = Op + (size_t)(b * Lseq + q0 + l31) * Dm + h * 64;
        // epilogue layout: lane owns col q = l31; rows d = (r&3)+8*(r>>2)+4*hi
#pragma unroll
        for (int t = 0; t < 4; ++t) {
            bf16x4 p0, p1;
#pragma unroll
            for (int i = 0; i < 4; ++i) {
                p0[i] = (bf16)(o0[4 * t + i] * fa + r[(4 * t + i) * 64 + lane] * fb);
                p1[i] = (bf16)(o1[4 * t + i] * fa + r[1024 + (4 * t + i) * 64 + lane] * fb);
            }
            *(bf16x4*)(dst + 8 * t + 4 * hi) = p0;
            *(bf16x4*)(dst + 32 + 8 * t + 4 * hi) = p1;
        }
    }
}

// ---------------- launch ----------------
extern "C" void kernel_launch(void* const* d_in, const int* in_sizes, int n_in,
                              void* d_out, int out_size, void* d_ws, size_t ws_size,
                              hipStream_t stream) {
    (void)in_sizes; (void)n_in; (void)out_size; (void)ws_size;
    const float* x    = (const float*)d_in[0];
    const float* Wqkv = (const float*)d_in[1];
    const float* bqkv = (const float*)d_in[2];
    const float* Wout = (const float*)d_in[3];
    const float* bout = (const float*)d_in[4];
    float* out = (float*)d_out;
    char* ws = (char*)d_ws;

    bf16* xbf    = (bf16*)(ws + OFF_XATT);
    bf16* att    = (bf16*)(ws + OFF_XATT);   // aliases xbf (dead after gemm_qkv)
    bf16* wqkvT  = (bf16*)(ws + OFF_WQKVT);
    bf16* woutT  = (bf16*)(ws + OFF_WOUTT);
    float2* tab  = (float2*)(ws + OFF_TAB);
    bf16* qb     = (bf16*)(ws + OFF_Q);
    bf16* kb     = (bf16*)(ws + OFF_K);
    bf16* vt     = (bf16*)(ws + OFF_VT);

    (void)hipFuncSetAttribute((const void*)k_gemm_qkv256,
                              hipFuncAttributeMaxDynamicSharedMemorySize, 131072);

    hipLaunchKernelGGL(k_prep, dim3(NB_CONV + NB_TQ + NB_TO + NB_SC), dim3(256), 0, stream,
                       x, Wqkv, Wout, xbf, wqkvT, woutT, tab);
    hipLaunchKernelGGL(k_gemm_qkv256, dim3(192), dim3(512), 131072, stream,
                       xbf, wqkvT, bqkv, qb, kb, vt, tab);
    hipLaunchKernelGGL(k_attn, dim3(32 * 16), dim3(512), 0, stream, qb, kb, vt, att);
    hipLaunchKernelGGL(k_gemm_out, dim3(512), dim3(256), 0, stream,
                       att, woutT, bout, out);
}